// Round 5
// baseline (293.819 us; speedup 1.0000x reference)
//
#include <hip/hip_runtime.h>
#include <hip/hip_bf16.h>

// SparseDiffusionModel on MI355X — dtype-adaptive (fp32 or bf16 inputs; fp32
// confirmed active by round-4 counters).
//
// Algebra: everything between `features` and attention is affine in features,
// and the query is one token/batch:
//   score[i,h] = f_i . u[b,h] + cq[b,h]
//     u_h = Wtok@(Wk@(Wik[:,hblk]@q_h)) / sqrt(32)   (mat-vec chain per batch)
//     cq  = (tb . t1 + bik_h.q_h)/sqrt(32), tb = btok@Wk+bk, t1 = Wik[:,hblk]@q_h
//   ctx_h = ((wbar_h@Wtok+btok)@Wv+bv)@Wiv[:,hblk]+biv, wbar = softmax-wtd mean.
//
// Round-4 postmortem: kF was stalled (VALUBusy 16%) on contended device-scope
// atomics to l (64 hot lines x 1024 blocks) and w, drained by the post-flush
// __syncthreads and block retirement. This version is ATOMIC-FREE: per-block
// per-segment partials go to private slots (hdr/lpart/wpart); kE reduces them.
// kPre is deleted (mat-vec chains in kA/kE cost the same as precomputed mats).
//
// ws (floats): flag@0 | u@64[32768] | cq[256] | l_ovf[256] | w_ovf[32768]
//   | hdr[2048 ints] | lpart[8192] | wpart[2048*512 bf16 = 262144] ~ 1.36 MB

typedef unsigned short ushort_t;
typedef unsigned int uint_t;
typedef unsigned long long ull_t;

#define NB 64
#define CENC 128
#define HID 512
#define RSQRT32 0.17677669529663689f

#define WS_FLAG   0
#define WS_U      64
#define WS_CQ     32832
#define WS_LOVF   33088
#define WS_WOVF   33344
#define WS_HDR    66112
#define WS_LPART  68160
#define WS_WPART  76352

__device__ __forceinline__ float blo(uint_t u){ return __uint_as_float(u << 16); }
__device__ __forceinline__ float bhi(uint_t u){ return __uint_as_float(u & 0xffff0000u); }
__device__ __forceinline__ float bf2f(ushort_t h){ return __uint_as_float(((uint_t)h) << 16); }
__device__ __forceinline__ ushort_t f2bf(float f){
    uint_t u = __float_as_uint(f);
    u += 0x7fffu + ((u >> 16) & 1u);   // RNE
    return (ushort_t)(u >> 16);
}

template<bool BF16> struct Ld;
template<> struct Ld<true> {
    static __device__ __forceinline__ float at(const void* p, long i) {
        return __uint_as_float(((uint_t)((const ushort_t*)p)[i]) << 16);
    }
};
template<> struct Ld<false> {
    static __device__ __forceinline__ float at(const void* p, long i) {
        return ((const float*)p)[i];
    }
};

// Per-block dtype detection on first 4096 ushorts of features.
// fp32 buffer: random mantissa halves -> some bf16-exp field >=140.
// fp32 holding bf16-rounded: low halves all zero. else: true bf16.
__device__ int detect_bf16(const ushort_t* f, int tid, int nthr, int* sh2) {
    if (tid == 0) { sh2[0] = 0; sh2[1] = 0; }
    __syncthreads();
    int myb = 0, myz = 0;
    for (int i = tid; i < 4096; i += nthr) {
        ushort_t v = f[i];
        if (((v >> 7) & 0xff) >= 140) myb = 1;
        if (!(i & 1) && v == 0) myz++;
    }
    if (myb) atomicOr(&sh2[0], 1);
    atomicAdd(&sh2[1], myz);
    __syncthreads();
    return (sh2[0] || sh2[1] > 1024) ? 0 : 1;   // 1 = true bf16
}

// ---------------------------------------------------------------------------
// kA: per batch b (grid 64 x 256): zero overflow accumulators; emb -> t_h -> y
// -> q0 -> qL; then per head the mat-vec chain for u and cq.
template<bool BF16>
__device__ void kA_impl(int b, int tid,
    const void* y_t, const int* t,
    const void* Wt, const void* bt, const void* Win, const void* bin_,
    const void* Wq, const void* bq, const void* Wiq, const void* biq,
    const void* Wtok, const void* btok, const void* Wk, const void* bk,
    const void* Wik, const void* bik,
    float* u_out, float* cq_out, float* w_ovf, float* l_ovf, float* sh)
{
    using L = Ld<BF16>;
    float* emb = sh;          // 64
    float* y   = sh + 64;     // 512
    float* p2  = sh + 576;    // 256
    float* q0  = sh + 832;    // 128 (reused as t2)
    float* qL  = sh + 960;    // 128
    float* tb  = sh + 1088;   // 128
    float* t1  = sh + 1216;   // 128
    float* t2  = q0;
    int tid2 = tid & 127, half = tid >> 7;

    for (int i = tid; i < 512; i += 256) w_ovf[b*512 + i] = 0.f;
    if (tid < 4) l_ovf[b*4 + tid] = 0.f;

    if (tid < 32) {
        float fr = __expf(-(float)tid * 0.28782313662425576f); // ln(1e4)/32
        float arg = (float)t[b] * fr;
        emb[tid]      = sinf(arg);
        emb[tid + 32] = cosf(arg);
    }
    __syncthreads();

    float yt0 = L::at(y_t, b*3+0), yt1 = L::at(y_t, b*3+1), yt2 = L::at(y_t, b*3+2);
    for (int rep = 0; rep < 2; rep++) {
        int o = tid + rep*256;
        float acc = L::at(bt, o);
        for (int k = 0; k < 64; k++) acc += emb[k] * L::at(Wt, k*512+o);
        acc = fmaxf(acc, 0.f);
        y[o] = acc + L::at(bin_, o) + yt0*L::at(Win, o) + yt1*L::at(Win, 512+o)
             + yt2*L::at(Win, 1024+o);
    }
    __syncthreads();
    {   // q0 = y @ Wq + bq
        float acc = 0.f;
        for (int k = half*256; k < half*256+256; k++) acc += y[k] * L::at(Wq, k*128+tid2);
        p2[half*128 + tid2] = acc;
    }
    __syncthreads();
    if (tid < 128) q0[tid] = p2[tid] + p2[128+tid] + L::at(bq, tid);
    __syncthreads();
    {   // qL = q0 @ Wiq + biq
        float acc = 0.f;
        for (int k = half*64; k < half*64+64; k++) acc += q0[k] * L::at(Wiq, k*128+tid2);
        p2[half*128 + tid2] = acc;
    }
    __syncthreads();
    if (tid < 128) qL[tid] = p2[tid] + p2[128+tid] + L::at(biq, tid);
    __syncthreads();
    {   // tb = btok @ Wk + bk   (coalesced column access)
        float acc = 0.f;
        for (int k = half*64; k < half*64+64; k++)
            acc += L::at(btok, k) * L::at(Wk, k*128+tid2);
        p2[half*128 + tid2] = acc;
    }
    __syncthreads();
    if (tid < 128) tb[tid] = p2[tid] + p2[128+tid] + L::at(bk, tid);
    __syncthreads();

    for (int h = 0; h < 4; h++) {
        {   // t1[c2] = Wik[c2, hblk] . q_h   (per-thread row chunk, 64 B)
            float a = 0.f;
            for (int j = half*16; j < half*16+16; j++)
                a += L::at(Wik, tid2*128 + h*32 + j) * qL[h*32 + j];
            p2[half*128 + tid2] = a;
        }
        __syncthreads();
        if (tid < 128) t1[tid] = p2[tid] + p2[128+tid];
        __syncthreads();
        // cq[b,h] = (tb . t1 + bik_h . q_h) / sqrt(32)
        if (tid < 128) {
            float r = tb[tid] * t1[tid];
            if (tid < 32) r += L::at(bik, h*32 + tid) * qL[h*32 + tid];
            p2[tid] = r;
        }
        __syncthreads();
        for (int s = 64; s > 0; s >>= 1) { if (tid < s) p2[tid] += p2[tid+s]; __syncthreads(); }
        if (tid == 0) cq_out[b*4 + h] = p2[0] * RSQRT32;
        __syncthreads();
        {   // t2[c1] = Wk[c1,:] . t1   (per-thread row chunk, 256 B)
            float a = 0.f;
            for (int k = half*64; k < half*64+64; k++)
                a += L::at(Wk, tid2*128 + k) * t1[k];
            p2[half*128 + tid2] = a;
        }
        __syncthreads();
        if (tid < 128) t2[tid] = p2[tid] + p2[128+tid];
        __syncthreads();
        {   // u[c] = Wtok[c,:] . t2
            float a = 0.f;
            for (int k = half*64; k < half*64+64; k++)
                a += L::at(Wtok, tid2*128 + k) * t2[k];
            p2[half*128 + tid2] = a;
        }
        __syncthreads();
        if (tid < 128) u_out[b*512 + h*128 + tid] = (p2[tid] + p2[128+tid]) * RSQRT32;
        __syncthreads();
    }
}

__global__ __launch_bounds__(256) void kA(
    const ushort_t* __restrict__ fraw,
    const void* y_t, const int* t,
    const void* Wt, const void* bt, const void* Win, const void* bin_,
    const void* Wq, const void* bq, const void* Wiq, const void* biq,
    const void* Wtok, const void* btok, const void* Wk, const void* bk,
    const void* Wik, const void* bik,
    float* ws)
{
    __shared__ int sh2[2];
    __shared__ float sh[1344];
    int flag = detect_bf16(fraw, threadIdx.x, 256, sh2);
    if (blockIdx.x == 0 && threadIdx.x == 0) *(int*)(ws + WS_FLAG) = flag;
    if (flag) kA_impl<true >(blockIdx.x, threadIdx.x, y_t,t,Wt,bt,Win,bin_,Wq,bq,Wiq,biq,
                             Wtok,btok,Wk,bk,Wik,bik,
                             ws+WS_U, ws+WS_CQ, ws+WS_WOVF, ws+WS_LOVF, sh);
    else      kA_impl<false>(blockIdx.x, threadIdx.x, y_t,t,Wt,bt,Win,bin_,Wq,bq,Wiq,biq,
                             Wtok,btok,Wk,bk,Wik,bik,
                             ws+WS_U, ws+WS_CQ, ws+WS_WOVF, ws+WS_LOVF, sh);
}

// ---------------------------------------------------------------------------
// kF: fused streaming pass, ATOMIC-FREE. 256 thr, 128 tokens/block.
// Per sorted-batch segment (<=2/block in practice): phase 1 computes
// e=exp(score) into LDS (16 lanes/token, shfl_xor(16) reduce, u in named
// float4 regs); phase 2 accumulates the e-weighted feature sum and stores a
// bf16 partial to the block's private slot. kE reduces slots later.
struct alignas(16) KFS {
    ushort_t tile[128*136];    // 34816 B; stride 136 keeps uint4 alignment
    float eL[128*4];
    float red[16*4];
    int lb[128];
    int starts[129];
    ull_t smask[2];
    int nseg;
    int sh2pad[4];
};

__global__ __launch_bounds__(256, 4) void kF(
    const void* __restrict__ features, const int* __restrict__ batch_idx,
    float* __restrict__ ws)
{
    extern __shared__ char smemraw[];
    KFS* S = (KFS*)smemraw;
    const int base = blockIdx.x * 128;
    const int tau = threadIdx.x;
    const float* u  = ws + WS_U;
    const float* cq = ws + WS_CQ;
    float* l_ovf = ws + WS_LOVF;
    float* w_ovf = ws + WS_WOVF;
    int*   hdr   = (int*)(ws + WS_HDR);
    float* lpart = ws + WS_LPART;
    ushort_t* wpart = (ushort_t*)(ws + WS_WPART);

    const int flag = *(const int*)(ws + WS_FLAG);

    if (flag) {                  // true bf16 input: raw copy
        const ushort_t* src = (const ushort_t*)features + (size_t)base * 128;
        #pragma unroll
        for (int s = 0; s < 8; s++) {
            int idx = s * 256 + tau;
            int ui = idx * 8;
            int tok = ui >> 7, ch = ui & 127;
            uint4 v = ((const uint4*)src)[idx];
            *(uint4*)&S->tile[tok*136 + ch] = v;
        }
    } else {                     // fp32 input: convert to bf16 (RNE)
        const float* src = (const float*)features + (size_t)base * 128;
        #pragma unroll
        for (int s = 0; s < 16; s++) {
            int idx = s * 256 + tau;
            int fi = idx * 4;
            int tok = fi >> 7, ch = fi & 127;
            float4 v = ((const float4*)src)[idx];
            uint_t lo = (uint_t)f2bf(v.x) | ((uint_t)f2bf(v.y) << 16);
            uint_t hi = (uint_t)f2bf(v.z) | ((uint_t)f2bf(v.w) << 16);
            *(uint2*)&S->tile[tok*136 + ch] = make_uint2(lo, hi);
        }
    }
    if (tau < 128) S->lb[tau] = batch_idx[base + tau];
    __syncthreads();

    bool isstart = (tau < 128) && (tau == 0 || S->lb[tau] != S->lb[tau-1]);
    ull_t m = __ballot(isstart);
    int wv = tau >> 6, lane = tau & 63;
    if (wv < 2 && lane == 0) S->smask[wv] = m;
    __syncthreads();
    if (isstart) {
        int rank = ((wv == 1) ? __popcll(S->smask[0]) : 0)
                 + __popcll(m & ((1ull << lane) - 1ull));
        S->starts[rank] = tau;
    }
    if (tau == 0) S->nseg = __popcll(S->smask[0]) + __popcll(S->smask[1]);
    __syncthreads();

    const int nseg = S->nseg;
    if (tau < 2) hdr[blockIdx.x*2 + tau] = (tau < nseg) ? S->lb[S->starts[tau]] : -1;

    const int qq = tau & 15, grp = tau >> 4;
    const int c = tau & 127, hp = tau >> 7;   // hp: heads {2hp, 2hp+1}

    for (int s = 0; s < nseg; s++) {
        const int lo = S->starts[s];
        const int hi = (s + 1 < nseg) ? S->starts[s+1] : 128;
        const int b = S->lb[lo];
        const bool slotpath = (s < 2);
        const int slot = blockIdx.x*2 + s;

        const float* ub = u + b*512 + qq*8;
        float4 u0a = *(const float4*)(ub + 0),   u0b = *(const float4*)(ub + 4);
        float4 u1a = *(const float4*)(ub + 128), u1b = *(const float4*)(ub + 132);
        float4 u2a = *(const float4*)(ub + 256), u2b = *(const float4*)(ub + 260);
        float4 u3a = *(const float4*)(ub + 384), u3b = *(const float4*)(ub + 388);
        float4 cqr = *(const float4*)(cq + b*4);

        float l0=0.f, l1=0.f, l2=0.f, l3=0.f;
        for (int tok = lo + grp; tok < hi; tok += 16) {
            uint4 fv = *(const uint4*)&S->tile[tok*136 + qq*8];
            float f0=blo(fv.x), f1=bhi(fv.x), f2=blo(fv.y), f3=bhi(fv.y);
            float f4=blo(fv.z), f5=bhi(fv.z), f6=blo(fv.w), f7=bhi(fv.w);
            float p0 = f0*u0a.x+f1*u0a.y+f2*u0a.z+f3*u0a.w+f4*u0b.x+f5*u0b.y+f6*u0b.z+f7*u0b.w;
            float p1 = f0*u1a.x+f1*u1a.y+f2*u1a.z+f3*u1a.w+f4*u1b.x+f5*u1b.y+f6*u1b.z+f7*u1b.w;
            float p2 = f0*u2a.x+f1*u2a.y+f2*u2a.z+f3*u2a.w+f4*u2b.x+f5*u2b.y+f6*u2b.z+f7*u2b.w;
            float p3 = f0*u3a.x+f1*u3a.y+f2*u3a.z+f3*u3a.w+f4*u3b.x+f5*u3b.y+f6*u3b.z+f7*u3b.w;
            #pragma unroll
            for (int mm = 1; mm < 16; mm <<= 1) {
                p0 += __shfl_xor(p0, mm, 16);
                p1 += __shfl_xor(p1, mm, 16);
                p2 += __shfl_xor(p2, mm, 16);
                p3 += __shfl_xor(p3, mm, 16);
            }
            if (qq == 0) {
                float e0 = __expf(fminf(p0 + cqr.x, 30.f));
                float e1 = __expf(fminf(p1 + cqr.y, 30.f));
                float e2 = __expf(fminf(p2 + cqr.z, 30.f));
                float e3 = __expf(fminf(p3 + cqr.w, 30.f));
                *(float4*)&S->eL[tok*4] = make_float4(e0, e1, e2, e3);
                l0 += e0; l1 += e1; l2 += e2; l3 += e3;
            }
        }
        if (qq == 0) *(float4*)&S->red[grp*4] = make_float4(l0, l1, l2, l3);
        __syncthreads();   // eL + red ready

        if (tau < 4) {
            float ls = 0.f;
            #pragma unroll
            for (int g = 0; g < 16; g++) ls += S->red[g*4 + tau];
            if (slotpath) lpart[slot*4 + tau] = ls;
            else atomicAdd(&l_ovf[b*4 + tau], ls);
        }

        // phase 2: lane=channel, two heads per thread, full token range
        float a0 = 0.f, a1 = 0.f;
        for (int tok = lo; tok < hi; tok++) {
            float fvv = bf2f(S->tile[tok*136 + c]);
            float2 e = *(const float2*)&S->eL[tok*4 + 2*hp];
            a0 += e.x * fvv; a1 += e.y * fvv;
        }
        if (slotpath) {
            wpart[slot*512 + (2*hp)*128 + c]   = f2bf(a0);
            wpart[slot*512 + (2*hp+1)*128 + c] = f2bf(a1);
        } else {
            atomicAdd(&w_ovf[b*512 + (2*hp)*128 + c], a0);
            atomicAdd(&w_ovf[b*512 + (2*hp+1)*128 + c], a1);
        }
        __syncthreads();   // protect eL/red before next segment
    }
}

// ---------------------------------------------------------------------------
// kE: per batch (grid 64 x 256): reduce partial slots -> wbar; then the
// v-chain per head; attn out; final MLP -> out.
template<bool BF16>
__device__ void kE_impl(int b, int tid, float* ws,
    const void* Wtok, const void* btok, const void* Wv, const void* bv,
    const void* Wiv, const void* biv, const void* Wo, const void* bo,
    const void* Wco, const void* bco, const void* Wout, const void* bout,
    void* out, float* sh, int* shi)
{
    using L = Ld<BF16>;
    float* wb  = sh;           // 512 [h*128+c]
    float* p2  = sh + 512;     // 256
    float* s1  = sh + 768;     // 128
    float* s2  = sh + 896;     // 128
    float* ctx = sh + 1024;    // 128
    float* ao  = sh + 1152;    // 128
    float* y2  = sh + 1280;    // 512
    float* linv= sh + 1792;    // 4
    int* mslot = shi;          // 64
    int* manyp = shi + 64;     // 1

    const int* hdr = (const int*)(ws + WS_HDR);
    const float* lpart = ws + WS_LPART;
    const ushort_t* wpart = (const ushort_t*)(ws + WS_WPART);
    const float* l_ovf = ws + WS_LOVF;
    const float* w_ovf = ws + WS_WOVF;

    int tid2 = tid & 127, half = tid >> 7;
    int ch0 = tid, ch1 = tid + 256;
    float a0 = 0.f, a1 = 0.f, lacc = 0.f;

    for (int cb = 0; cb < 2048; cb += 64) {
        if (tid < 64) {
            int hv = hdr[cb + tid];
            bool mt = (hv == b);
            ull_t mk = __ballot(mt);
            mslot[tid] = mt ? (cb + tid) : -1;
            if (tid == 0) *manyp = (mk != 0ull) ? 1 : 0;
        }
        __syncthreads();
        if (*manyp) {
            for (int j = 0; j < 64; j++) {
                int s = mslot[j];
                if (s >= 0) {
                    a0 += bf2f(wpart[s*512 + ch0]);
                    a1 += bf2f(wpart[s*512 + ch1]);
                    if (tid < 4) lacc += lpart[s*4 + tid];
                }
            }
        }
        __syncthreads();
    }
    a0 += w_ovf[b*512 + ch0];
    a1 += w_ovf[b*512 + ch1];
    if (tid < 4) {
        lacc += l_ovf[b*4 + tid];
        linv[tid] = (lacc > 1e-30f) ? 1.f/lacc : 0.f;
    }
    __syncthreads();
    wb[ch0] = a0 * linv[ch0 >> 7];
    wb[ch1] = a1 * linv[ch1 >> 7];
    __syncthreads();

    for (int h = 0; h < 4; h++) {
        {   // s1 = wbar_h @ Wtok + btok
            float a = 0.f;
            for (int k = half*64; k < half*64+64; k++)
                a += wb[h*128 + k] * L::at(Wtok, k*128 + tid2);
            p2[half*128 + tid2] = a;
        }
        __syncthreads();
        if (tid < 128) s1[tid] = p2[tid] + p2[128+tid] + L::at(btok, tid);
        __syncthreads();
        {   // s2 = s1 @ Wv + bv
            float a = 0.f;
            for (int k = half*64; k < half*64+64; k++)
                a += s1[k] * L::at(Wv, k*128 + tid2);
            p2[half*128 + tid2] = a;
        }
        __syncthreads();
        if (tid < 128) s2[tid] = p2[tid] + p2[128+tid] + L::at(bv, tid);
        __syncthreads();
        {   // ctx[hblk] = s2 @ Wiv[:,hblk] + biv
            int d = tid & 31, q8 = tid >> 5;
            float a = 0.f;
            for (int k = q8*16; k < q8*16+16; k++)
                a += s2[k] * L::at(Wiv, k*128 + h*32 + d);
            p2[q8*32 + d] = a;
        }
        __syncthreads();
        if (tid < 32) {
            float a = L::at(biv, h*32 + tid);
            #pragma unroll
            for (int q = 0; q < 8; q++) a += p2[q*32 + tid];
            ctx[h*32 + tid] = a;
        }
        __syncthreads();
    }

    {   // ao = ctx @ Wo + bo
        float a = 0.f;
        for (int k = half*64; k < half*64+64; k++)
            a += ctx[k] * L::at(Wo, k*128 + tid2);
        p2[half*128 + tid2] = a;
    }
    __syncthreads();
    if (tid < 128) ao[tid] = p2[tid] + p2[128+tid] + L::at(bo, tid);
    __syncthreads();
    for (int rep = 0; rep < 2; rep++) {
        int o = tid + rep*256;
        float a = L::at(bco, o);
        for (int k = 0; k < 128; k++) a += ao[k] * L::at(Wco, k*512 + o);
        y2[o] = a;
    }
    __syncthreads();
    for (int o = 0; o < 3; o++) {
        float p = y2[tid]*L::at(Wout, tid*3+o) + y2[tid+256]*L::at(Wout, (tid+256)*3+o);
        p2[tid] = p;
        __syncthreads();
        for (int st = 128; st > 0; st >>= 1) { if (tid < st) p2[tid] += p2[tid+st]; __syncthreads(); }
        if (tid == 0) {
            float val = p2[0] + L::at(bout, o);
            if (BF16) ((ushort_t*)out)[b*3+o] = f2bf(val);
            else      ((float*)out)[b*3+o] = val;
        }
        __syncthreads();
    }
}

__global__ __launch_bounds__(256) void kE(
    float* ws,
    const void* Wtok, const void* btok, const void* Wv, const void* bv,
    const void* Wiv, const void* biv, const void* Wo, const void* bo,
    const void* Wco, const void* bco, const void* Wout, const void* bout,
    void* out)
{
    __shared__ float sh[1800];
    __shared__ int shi[66];
    int flag = *(const int*)(ws + WS_FLAG);
    if (flag) kE_impl<true >(blockIdx.x, threadIdx.x, ws, Wtok,btok,Wv,bv,Wiv,biv,
                             Wo,bo,Wco,bco,Wout,bout,out,sh,shi);
    else      kE_impl<false>(blockIdx.x, threadIdx.x, ws, Wtok,btok,Wv,bv,Wiv,biv,
                             Wo,bo,Wco,bco,Wout,bout,out,sh,shi);
}

// ---------------------------------------------------------------------------
extern "C" void kernel_launch(void* const* d_in, const int* in_sizes, int n_in,
                              void* d_out, int out_size, void* d_ws, size_t ws_size,
                              hipStream_t stream)
{
    const void* features = d_in[0];
    const int*  batch_idx= (const int*)d_in[1];
    const void* y_t      = d_in[2];
    const int*  t        = (const int*)d_in[3];
    // d_in[4] = N_max (unused)
    const void *Wtok=d_in[5],  *btok=d_in[6];
    const void *Wt  =d_in[7],  *bt  =d_in[8];
    const void *Win =d_in[9],  *bin_=d_in[10];
    const void *Wq  =d_in[11], *bq  =d_in[12];
    const void *Wk  =d_in[13], *bk  =d_in[14];
    const void *Wv  =d_in[15], *bv  =d_in[16];
    const void *Wiq =d_in[17], *biq =d_in[18];
    const void *Wik =d_in[19], *bik =d_in[20];
    const void *Wiv =d_in[21], *biv =d_in[22];
    const void *Wo  =d_in[23], *bo  =d_in[24];
    const void *Wco =d_in[25], *bco =d_in[26];
    const void *Wout=d_in[27], *bout=d_in[28];

    int N = in_sizes[0] / CENC;   // 131072
    float* ws = (float*)d_ws;

    kA<<<NB, 256, 0, stream>>>((const ushort_t*)features, y_t, t,
        Wt, bt, Win, bin_, Wq, bq, Wiq, biq, Wtok, btok, Wk, bk, Wik, bik, ws);
    kF<<<N / 128, 256, sizeof(KFS), stream>>>(features, batch_idx, ws);
    kE<<<NB, 256, 0, stream>>>(ws, Wtok, btok, Wv, bv, Wiv, biv, Wo, bo,
                               Wco, bco, Wout, bout, d_out);
}

// Round 6
// 217.772 us; speedup vs baseline: 1.3492x; 1.3492x over previous
//
#include <hip/hip_runtime.h>
#include <hip/hip_bf16.h>

// SparseDiffusionModel on MI355X — dtype-adaptive (fp32 confirmed active).
//
// Algebra: everything between `features` and attention is affine in features;
// query is one token/batch:
//   score[i,h] = f_i . u[b,h] + cq[b,h],  u_h = Wtok@(Wk@(Wik[:,hblk]@q_h))/sqrt32
//   ctx_h = ((wbar_h@Wtok+btok)@Wv+bv)@Wiv[:,hblk]+biv, wbar = softmax-wtd mean.
//
// Round-5 postmortem: kE 105us at 0.9% VALUBusy — latency-serialized slot SCAN
// (32 barrier-chunks x ~900cyc cross-XCD misses) + ~40 serial matvec stages.
// This round: per-batch slot LISTS (no scan), head-folded stages (acc[4]),
// kF tile-less with full-row phase-1 dots and 4-way-split unrolled phase 2.
//
// ws (floats): flag | cnt[64 i32] | slot[64*32 i32] | u[32768] | cq[256]
//   | l_ovf[256] | w_ovf[32768] | lpart[8192] | wpart[2048*512 bf16] ~1.35 MB

typedef unsigned short ushort_t;
typedef unsigned int uint_t;
typedef unsigned long long ull_t;

#define NB 64
#define CENC 128
#define HID 512
#define RSQRT32 0.17677669529663689f

#define WS_FLAG   0
#define WS_CNT    64
#define WS_SLOT   128
#define WS_U      2176
#define WS_CQ     34944
#define WS_LOVF   35200
#define WS_WOVF   35456
#define WS_LPART  68224
#define WS_WPART  76416

__device__ __forceinline__ float bf2f(ushort_t h){ return __uint_as_float(((uint_t)h) << 16); }
__device__ __forceinline__ ushort_t f2bf(float f){
    uint_t u = __float_as_uint(f);
    u += 0x7fffu + ((u >> 16) & 1u);   // RNE
    return (ushort_t)(u >> 16);
}

template<bool BF16> struct Ld;
template<> struct Ld<true> {
    static __device__ __forceinline__ float at(const void* p, long i) {
        return __uint_as_float(((uint_t)((const ushort_t*)p)[i]) << 16);
    }
};
template<> struct Ld<false> {
    static __device__ __forceinline__ float at(const void* p, long i) {
        return ((const float*)p)[i];
    }
};

// dtype detection on first 4096 ushorts of features (see r2/r3 notes).
__device__ int detect_bf16(const ushort_t* f, int tid, int* sh2) {
    if (tid == 0) { sh2[0] = 0; sh2[1] = 0; }
    __syncthreads();
    int myb = 0, myz = 0;
    for (int i = tid; i < 4096; i += 256) {
        ushort_t v = f[i];
        if (((v >> 7) & 0xff) >= 140) myb = 1;
        if (!(i & 1) && v == 0) myz++;
    }
    if (myb) atomicOr(&sh2[0], 1);
    atomicAdd(&sh2[1], myz);
    __syncthreads();
    return (sh2[0] || sh2[1] > 1024) ? 0 : 1;   // 1 = true bf16
}

// ---------------------------------------------------------------------------
// kA: per batch (64 x 256): zero accumulators; emb->y->q0->qL; head-folded
// chain t1 -> (cq) -> t2 -> u.
template<bool BF16>
__device__ void kA_impl(int b, int tid,
    const void* y_t, const int* t,
    const void* Wt, const void* bt, const void* Win, const void* bin_,
    const void* Wq, const void* bq, const void* Wiq, const void* biq,
    const void* Wtok, const void* btok, const void* Wk, const void* bk,
    const void* Wik, const void* bik, float* ws, float* sh)
{
    using L = Ld<BF16>;
    float* emb = sh;            // 64
    float* y   = sh + 64;       // 512
    float* p2  = sh + 576;      // 256
    float* q0  = sh + 832;      // 128
    float* qL  = sh + 960;      // 128
    float* tb  = sh + 1088;     // 128
    float* t1a = sh + 1216;     // 512
    float* t2a = sh + 1728;     // 512
    float* p1k = sh + 2240;     // 1024
    float* u_out  = ws + WS_U;
    float* cq_out = ws + WS_CQ;

    const int c = tid & 127, pair = tid >> 7;

    for (int i = tid; i < 512; i += 256) ws[WS_WOVF + b*512 + i] = 0.f;
    if (tid < 4) ws[WS_LOVF + b*4 + tid] = 0.f;
    if (tid == 0) ((int*)ws)[WS_CNT + b] = 0;

    if (tid < 32) {
        float fr = __expf(-(float)tid * 0.28782313662425576f); // ln(1e4)/32
        float arg = (float)t[b] * fr;
        emb[tid]      = sinf(arg);
        emb[tid + 32] = cosf(arg);
    }
    __syncthreads();

    float yt0 = L::at(y_t, b*3+0), yt1 = L::at(y_t, b*3+1), yt2 = L::at(y_t, b*3+2);
    #pragma unroll
    for (int rep = 0; rep < 2; rep++) {
        int o = tid + rep*256;
        float acc = L::at(bt, o);
        #pragma unroll
        for (int k = 0; k < 64; k++) acc += emb[k] * L::at(Wt, (long)k*512 + o);
        acc = fmaxf(acc, 0.f);
        y[o] = acc + L::at(bin_, o) + yt0*L::at(Win, o) + yt1*L::at(Win, 512+o)
             + yt2*L::at(Win, 1024+o);
    }
    __syncthreads();
    {   // q0 = y @ Wq + bq
        float acc = 0.f;
        #pragma unroll
        for (int k4 = 0; k4 < 256; k4 += 4) {
            int kk = pair*256 + k4;
            float4 y4 = *(const float4*)&y[kk];
            acc += y4.x*L::at(Wq,(long)kk*128+c)     + y4.y*L::at(Wq,(long)(kk+1)*128+c)
                 + y4.z*L::at(Wq,(long)(kk+2)*128+c) + y4.w*L::at(Wq,(long)(kk+3)*128+c);
        }
        p2[pair*128 + c] = acc;
    }
    __syncthreads();
    if (tid < 128) q0[tid] = p2[tid] + p2[128+tid] + L::at(bq, tid);
    __syncthreads();
    {   // qL = q0 @ Wiq + biq
        float acc = 0.f;
        #pragma unroll
        for (int k4 = 0; k4 < 64; k4 += 4) {
            int kk = pair*64 + k4;
            float4 q4 = *(const float4*)&q0[kk];
            acc += q4.x*L::at(Wiq,(long)kk*128+c)     + q4.y*L::at(Wiq,(long)(kk+1)*128+c)
                 + q4.z*L::at(Wiq,(long)(kk+2)*128+c) + q4.w*L::at(Wiq,(long)(kk+3)*128+c);
        }
        p2[pair*128 + c] = acc;
    }
    __syncthreads();
    if (tid < 128) qL[tid] = p2[tid] + p2[128+tid] + L::at(biq, tid);
    __syncthreads();
    {   // tb = btok @ Wk + bk
        float acc = 0.f;
        #pragma unroll
        for (int k4 = 0; k4 < 64; k4 += 4) {
            int kk = pair*64 + k4;
            acc += L::at(btok,kk)  *L::at(Wk,(long)kk*128+c)
                 + L::at(btok,kk+1)*L::at(Wk,(long)(kk+1)*128+c)
                 + L::at(btok,kk+2)*L::at(Wk,(long)(kk+2)*128+c)
                 + L::at(btok,kk+3)*L::at(Wk,(long)(kk+3)*128+c);
        }
        p2[pair*128 + c] = acc;
    }
    __syncthreads();
    if (tid < 128) tb[tid] = p2[tid] + p2[128+tid] + L::at(bk, tid);
    __syncthreads();
    {   // t1[h][c] = Wik[c, h*32+j] . qL_h   (heads folded)
        float a0=0.f, a1=0.f, a2=0.f, a3=0.f;
        #pragma unroll
        for (int j = 0; j < 16; j++) {
            int jj = pair*16 + j;
            a0 += L::at(Wik,(long)c*128 +  0 + jj) * qL[ 0 + jj];
            a1 += L::at(Wik,(long)c*128 + 32 + jj) * qL[32 + jj];
            a2 += L::at(Wik,(long)c*128 + 64 + jj) * qL[64 + jj];
            a3 += L::at(Wik,(long)c*128 + 96 + jj) * qL[96 + jj];
        }
        p1k[pair*512 +   0 + c] = a0; p1k[pair*512 + 128 + c] = a1;
        p1k[pair*512 + 256 + c] = a2; p1k[pair*512 + 384 + c] = a3;
    }
    __syncthreads();
    t1a[tid]     = p1k[tid]     + p1k[512+tid];
    t1a[tid+256] = p1k[tid+256] + p1k[768+tid];
    __syncthreads();
    {   // cq per head: wave h
        int hw = tid >> 6, lam = tid & 63;
        float r = tb[lam]*t1a[hw*128+lam] + tb[lam+64]*t1a[hw*128+64+lam];
        if (lam < 32) r += L::at(bik, hw*32+lam) * qL[hw*32+lam];
        #pragma unroll
        for (int mm = 1; mm < 64; mm <<= 1) r += __shfl_xor(r, mm, 64);
        if (lam == 0) cq_out[b*4 + hw] = r * RSQRT32;
    }
    {   // t2[h][c] = Wk[c,:] . t1[h]  (weight row shared across heads)
        float a0=0.f, a1=0.f, a2=0.f, a3=0.f;
        #pragma unroll
        for (int k4 = 0; k4 < 64; k4 += 4) {
            int kk = pair*64 + k4;
            float wa = L::at(Wk,(long)c*128+kk),   wbv = L::at(Wk,(long)c*128+kk+1);
            float wc = L::at(Wk,(long)c*128+kk+2), wd  = L::at(Wk,(long)c*128+kk+3);
            float4 t0 = *(const float4*)&t1a[kk],     t1v = *(const float4*)&t1a[128+kk];
            float4 t2v = *(const float4*)&t1a[256+kk], t3v = *(const float4*)&t1a[384+kk];
            a0 += wa*t0.x + wbv*t0.y + wc*t0.z + wd*t0.w;
            a1 += wa*t1v.x + wbv*t1v.y + wc*t1v.z + wd*t1v.w;
            a2 += wa*t2v.x + wbv*t2v.y + wc*t2v.z + wd*t2v.w;
            a3 += wa*t3v.x + wbv*t3v.y + wc*t3v.z + wd*t3v.w;
        }
        p1k[pair*512 +   0 + c] = a0; p1k[pair*512 + 128 + c] = a1;
        p1k[pair*512 + 256 + c] = a2; p1k[pair*512 + 384 + c] = a3;
    }
    __syncthreads();
    t2a[tid]     = p1k[tid]     + p1k[512+tid];
    t2a[tid+256] = p1k[tid+256] + p1k[768+tid];
    __syncthreads();
    {   // u[h][c] = Wtok[c,:] . t2[h]
        float a0=0.f, a1=0.f, a2=0.f, a3=0.f;
        #pragma unroll
        for (int k4 = 0; k4 < 64; k4 += 4) {
            int kk = pair*64 + k4;
            float wa = L::at(Wtok,(long)c*128+kk),   wbv = L::at(Wtok,(long)c*128+kk+1);
            float wc = L::at(Wtok,(long)c*128+kk+2), wd  = L::at(Wtok,(long)c*128+kk+3);
            float4 t0 = *(const float4*)&t2a[kk],     t1v = *(const float4*)&t2a[128+kk];
            float4 t2v = *(const float4*)&t2a[256+kk], t3v = *(const float4*)&t2a[384+kk];
            a0 += wa*t0.x + wbv*t0.y + wc*t0.z + wd*t0.w;
            a1 += wa*t1v.x + wbv*t1v.y + wc*t1v.z + wd*t1v.w;
            a2 += wa*t2v.x + wbv*t2v.y + wc*t2v.z + wd*t2v.w;
            a3 += wa*t3v.x + wbv*t3v.y + wc*t3v.z + wd*t3v.w;
        }
        p1k[pair*512 +   0 + c] = a0; p1k[pair*512 + 128 + c] = a1;
        p1k[pair*512 + 256 + c] = a2; p1k[pair*512 + 384 + c] = a3;
    }
    __syncthreads();
    u_out[b*512 + tid]     = (p1k[tid]     + p1k[512+tid]) * RSQRT32;
    u_out[b*512 + tid+256] = (p1k[tid+256] + p1k[768+tid]) * RSQRT32;
}

__global__ __launch_bounds__(256) void kA(
    const ushort_t* __restrict__ fraw,
    const void* y_t, const int* t,
    const void* Wt, const void* bt, const void* Win, const void* bin_,
    const void* Wq, const void* bq, const void* Wiq, const void* biq,
    const void* Wtok, const void* btok, const void* Wk, const void* bk,
    const void* Wik, const void* bik, float* ws)
{
    __shared__ int sh2[2];
    __shared__ float sh[3264];
    int flag = detect_bf16(fraw, threadIdx.x, sh2);
    if (blockIdx.x == 0 && threadIdx.x == 0) *(int*)(ws + WS_FLAG) = flag;
    if (flag) kA_impl<true >(blockIdx.x, threadIdx.x, y_t,t,Wt,bt,Win,bin_,Wq,bq,
                             Wiq,biq,Wtok,btok,Wk,bk,Wik,bik, ws, sh);
    else      kA_impl<false>(blockIdx.x, threadIdx.x, y_t,t,Wt,bt,Win,bin_,Wq,bq,
                             Wiq,biq,Wtok,btok,Wk,bk,Wik,bik, ws, sh);
}

// ---------------------------------------------------------------------------
// kF: streaming pass (1024 x 256), tile-less, atomic-free (slot lists).
// Phase 1: thread (tok, head-pair) full-row dot vs u (wave-uniform ptr).
// Phase 2: thread (2 channels, 4-way token split), cross-wave LDS combine.
template<bool BF16>
__device__ void kF_impl(const void* F, const int* __restrict__ batch_idx,
                        float* __restrict__ ws, int blk)
{
    using L = Ld<BF16>;
    __shared__ float eL[512];
    __shared__ float pp[2048];     // comp-major [8][256]
    __shared__ float red[8];
    __shared__ int lb[128];
    __shared__ int starts[129];
    __shared__ ull_t smask[2];
    __shared__ int nsegs;
    __shared__ int segslot[2];

    const int base = blk * 128;
    const int tau = threadIdx.x;
    const float* u   = ws + WS_U;
    const float* cqg = ws + WS_CQ;
    int* cnt      = (int*)ws + WS_CNT;
    int* slotlist = (int*)ws + WS_SLOT;
    float* l_ovf  = ws + WS_LOVF;
    float* w_ovf  = ws + WS_WOVF;
    float* lpart  = ws + WS_LPART;
    ushort_t* wpart = (ushort_t*)(ws + WS_WPART);

    if (tau < 128) lb[tau] = batch_idx[base + tau];
    __syncthreads();
    bool isstart = (tau < 128) && (tau == 0 || lb[tau] != lb[tau-1]);
    ull_t m = __ballot(isstart);
    const int wv = tau >> 6, lane = tau & 63;
    if (wv < 2 && lane == 0) smask[wv] = m;
    __syncthreads();
    if (isstart) {
        int rank = ((wv == 1) ? __popcll(smask[0]) : 0)
                 + __popcll(m & ((1ull << lane) - 1ull));
        starts[rank] = tau;
    }
    if (tau == 0) nsegs = __popcll(smask[0]) + __popcll(smask[1]);
    __syncthreads();
    const int nseg = nsegs;
    if (tau < 2) {
        int ss = -1;
        if (tau < nseg) {
            int bb = lb[starts[tau]];
            int idx = atomicAdd(&cnt[bb], 1);
            if (idx < 32) { slotlist[bb*32 + idx] = blk*2 + tau; ss = blk*2 + tau; }
        }
        segslot[tau] = ss;
    }
    __syncthreads();

    const int tok = tau & 127;
    const int hp  = __builtin_amdgcn_readfirstlane(tau >> 7);   // wave-uniform
    const int cA  = tau & 63, cB = cA + 64, sg4 = tau >> 6;

    for (int s = 0; s < nseg; s++) {
        const int lo = starts[s];
        const int hi = (s + 1 < nseg) ? starts[s+1] : 128;
        const int b  = lb[lo];
        const int slot = (s < 2) ? segslot[s] : -1;

        // ---- phase 1 ----
        const float* ur0 = u + b*512 + (2*hp)*128;
        const float* ur1 = ur0 + 128;
        float cq0 = cqg[b*4 + 2*hp], cq1 = cqg[b*4 + 2*hp + 1];
        bool act = (tok >= lo) && (tok < hi);
        float d0 = 0.f, d1 = 0.f;
        if (act) {
            long row = (long)(base + tok) * 128;
            #pragma unroll
            for (int k = 0; k < 128; k += 4) {
                float fa = L::at(F, row+k),   fb = L::at(F, row+k+1);
                float fc = L::at(F, row+k+2), fd = L::at(F, row+k+3);
                d0 += fa*ur0[k] + fb*ur0[k+1] + fc*ur0[k+2] + fd*ur0[k+3];
                d1 += fa*ur1[k] + fb*ur1[k+1] + fc*ur1[k+2] + fd*ur1[k+3];
            }
        }
        float e0 = act ? __expf(fminf(d0 + cq0, 30.f)) : 0.f;
        float e1 = act ? __expf(fminf(d1 + cq1, 30.f)) : 0.f;
        if (act) *(float2*)&eL[tok*4 + 2*hp] = make_float2(e0, e1);
        float s0 = e0, s1 = e1;
        #pragma unroll
        for (int mm = 1; mm < 64; mm <<= 1) {
            s0 += __shfl_xor(s0, mm, 64);
            s1 += __shfl_xor(s1, mm, 64);
        }
        if (lane == 0) { red[wv*2] = s0; red[wv*2+1] = s1; }
        __syncthreads();

        if (tau < 4) {
            int h = tau, g = h >> 1, j = h & 1;
            float ls = red[g*4 + j] + red[g*4 + 2 + j];
            if (slot >= 0) lpart[slot*4 + h] = ls;
            else atomicAdd(&l_ovf[b*4 + h], ls);
        }

        // ---- phase 2 ----
        float a0=0.f,a1=0.f,a2=0.f,a3=0.f,a4=0.f,a5=0.f,a6=0.f,a7=0.f;
        int tk = lo + sg4;
        for (; tk + 4 < hi; tk += 8) {
            float4 e0v = *(const float4*)&eL[tk*4];
            float4 e1v = *(const float4*)&eL[(tk+4)*4];
            float fA0 = L::at(F, (long)(base+tk)*128 + cA);
            float fB0 = L::at(F, (long)(base+tk)*128 + cB);
            float fA1 = L::at(F, (long)(base+tk+4)*128 + cA);
            float fB1 = L::at(F, (long)(base+tk+4)*128 + cB);
            a0 += e0v.x*fA0 + e1v.x*fA1; a1 += e0v.y*fA0 + e1v.y*fA1;
            a2 += e0v.z*fA0 + e1v.z*fA1; a3 += e0v.w*fA0 + e1v.w*fA1;
            a4 += e0v.x*fB0 + e1v.x*fB1; a5 += e0v.y*fB0 + e1v.y*fB1;
            a6 += e0v.z*fB0 + e1v.z*fB1; a7 += e0v.w*fB0 + e1v.w*fB1;
        }
        for (; tk < hi; tk += 4) {
            float4 ev = *(const float4*)&eL[tk*4];
            float fA = L::at(F, (long)(base+tk)*128 + cA);
            float fB = L::at(F, (long)(base+tk)*128 + cB);
            a0 += ev.x*fA; a1 += ev.y*fA; a2 += ev.z*fA; a3 += ev.w*fA;
            a4 += ev.x*fB; a5 += ev.y*fB; a6 += ev.z*fB; a7 += ev.w*fB;
        }
        int col = sg4*64 + cA;
        pp[0*256+col]=a0; pp[1*256+col]=a1; pp[2*256+col]=a2; pp[3*256+col]=a3;
        pp[4*256+col]=a4; pp[5*256+col]=a5; pp[6*256+col]=a6; pp[7*256+col]=a7;
        __syncthreads();
        #pragma unroll
        for (int rep = 0; rep < 2; rep++) {
            int i = tau + rep*256;           // flat h*128+ch
            int h = i >> 7, ch = i & 127;
            int comp = (ch < 64) ? h : (h + 4);
            int cc = ch & 63;
            float v = pp[comp*256 +   0 + cc] + pp[comp*256 +  64 + cc]
                    + pp[comp*256 + 128 + cc] + pp[comp*256 + 192 + cc];
            if (slot >= 0) wpart[(long)slot*512 + i] = f2bf(v);
            else atomicAdd(&w_ovf[b*512 + i], v);
        }
        __syncthreads();   // red/pp/eL reuse next segment
    }
}

__global__ __launch_bounds__(256) void kF(
    const void* __restrict__ features, const int* __restrict__ batch_idx,
    float* __restrict__ ws)
{
    if (*(const int*)(ws + WS_FLAG)) kF_impl<true >(features, batch_idx, ws, blockIdx.x);
    else                             kF_impl<false>(features, batch_idx, ws, blockIdx.x);
}

// ---------------------------------------------------------------------------
// kE: per batch (64 x 256): slot-list reduce -> wbar; head-folded v-chain;
// attn-out; final MLP -> out.
template<bool BF16>
__device__ void kE_impl(int b, int tid, float* ws,
    const void* Wtok, const void* btok, const void* Wv, const void* bv,
    const void* Wiv, const void* biv, const void* Wo, const void* bo,
    const void* Wco, const void* bco, const void* Wout, const void* bout,
    void* out, float* sh, int* shi)
{
    using L = Ld<BF16>;
    float* wb   = sh;            // 512
    float* s1a  = sh + 512;      // 512
    float* s2a  = sh + 1024;     // 512
    float* ctxa = sh + 1536;     // 128
    float* aoa  = sh + 1664;     // 128
    float* y2a  = sh + 1792;     // 512
    float* p1k  = sh + 2304;     // 1024
    float* linv = sh + 3328;     // 4

    const int c = tid & 127, pair = tid >> 7;
    const int* cnti = (const int*)ws;
    const ushort_t* wpart = (const ushort_t*)(ws + WS_WPART);

    int n = cnti[WS_CNT + b]; if (n > 32) n = 32;
    if (tid < 32) shi[tid] = (tid < n) ? cnti[WS_SLOT + b*32 + tid] : 0;
    __syncthreads();

    float a0 = 0.f, a1 = 0.f, lac = 0.f;
    for (int i = 0; i < n; i++) {
        int s = shi[i];
        a0 += bf2f(wpart[(long)s*512 + tid]);
        a1 += bf2f(wpart[(long)s*512 + tid + 256]);
    }
    if (tid < 4) for (int i = 0; i < n; i++) lac += ws[WS_LPART + shi[i]*4 + tid];
    a0 += ws[WS_WOVF + b*512 + tid];
    a1 += ws[WS_WOVF + b*512 + tid + 256];
    if (tid < 4) {
        lac += ws[WS_LOVF + b*4 + tid];
        linv[tid] = (lac > 1e-30f) ? 1.f/lac : 0.f;
    }
    __syncthreads();
    wb[tid]     = a0 * linv[tid >> 7];
    wb[tid+256] = a1 * linv[(tid+256) >> 7];
    __syncthreads();

    {   // s1[h][c] = wbar_h @ Wtok[:,c]  (heads folded; weight col shared)
        float b0=0.f,b1=0.f,b2=0.f,b3=0.f;
        #pragma unroll
        for (int k4 = 0; k4 < 64; k4 += 4) {
            int kk = pair*64 + k4;
            float wa = L::at(Wtok,(long)kk*128+c),     wbv = L::at(Wtok,(long)(kk+1)*128+c);
            float wc = L::at(Wtok,(long)(kk+2)*128+c), wd  = L::at(Wtok,(long)(kk+3)*128+c);
            float4 w0 = *(const float4*)&wb[kk],     w1 = *(const float4*)&wb[128+kk];
            float4 w2 = *(const float4*)&wb[256+kk], w3 = *(const float4*)&wb[384+kk];
            b0 += wa*w0.x + wbv*w0.y + wc*w0.z + wd*w0.w;
            b1 += wa*w1.x + wbv*w1.y + wc*w1.z + wd*w1.w;
            b2 += wa*w2.x + wbv*w2.y + wc*w2.z + wd*w2.w;
            b3 += wa*w3.x + wbv*w3.y + wc*w3.z + wd*w3.w;
        }
        p1k[pair*512 +   0 + c] = b0; p1k[pair*512 + 128 + c] = b1;
        p1k[pair*512 + 256 + c] = b2; p1k[pair*512 + 384 + c] = b3;
    }
    __syncthreads();
    s1a[tid]     = p1k[tid]     + p1k[512+tid]     + L::at(btok, tid & 127);
    s1a[tid+256] = p1k[tid+256] + p1k[768+tid]     + L::at(btok, (tid+256) & 127);
    __syncthreads();
    {   // s2[h][c] = s1_h @ Wv[:,c] + bv
        float b0=0.f,b1=0.f,b2=0.f,b3=0.f;
        #pragma unroll
        for (int k4 = 0; k4 < 64; k4 += 4) {
            int kk = pair*64 + k4;
            float wa = L::at(Wv,(long)kk*128+c),     wbv = L::at(Wv,(long)(kk+1)*128+c);
            float wc = L::at(Wv,(long)(kk+2)*128+c), wd  = L::at(Wv,(long)(kk+3)*128+c);
            float4 w0 = *(const float4*)&s1a[kk],     w1 = *(const float4*)&s1a[128+kk];
            float4 w2 = *(const float4*)&s1a[256+kk], w3 = *(const float4*)&s1a[384+kk];
            b0 += wa*w0.x + wbv*w0.y + wc*w0.z + wd*w0.w;
            b1 += wa*w1.x + wbv*w1.y + wc*w1.z + wd*w1.w;
            b2 += wa*w2.x + wbv*w2.y + wc*w2.z + wd*w2.w;
            b3 += wa*w3.x + wbv*w3.y + wc*w3.z + wd*w3.w;
        }
        p1k[pair*512 +   0 + c] = b0; p1k[pair*512 + 128 + c] = b1;
        p1k[pair*512 + 256 + c] = b2; p1k[pair*512 + 384 + c] = b3;
    }
    __syncthreads();
    s2a[tid]     = p1k[tid]     + p1k[512+tid] + L::at(bv, tid & 127);
    s2a[tid+256] = p1k[tid+256] + p1k[768+tid] + L::at(bv, (tid+256) & 127);
    __syncthreads();
    {   // ctx[o]= s2_h @ Wiv[:, o] (o = h*32+d)
        int h = c >> 5;
        float acc = 0.f;
        #pragma unroll
        for (int k4 = 0; k4 < 64; k4 += 4) {
            int kk = pair*64 + k4;
            float4 s4 = *(const float4*)&s2a[h*128 + kk];
            acc += s4.x*L::at(Wiv,(long)kk*128+c)     + s4.y*L::at(Wiv,(long)(kk+1)*128+c)
                 + s4.z*L::at(Wiv,(long)(kk+2)*128+c) + s4.w*L::at(Wiv,(long)(kk+3)*128+c);
        }
        p1k[pair*128 + c] = acc;
    }
    __syncthreads();
    if (tid < 128) ctxa[tid] = p1k[tid] + p1k[128+tid] + L::at(biv, tid);
    __syncthreads();
    {   // ao = ctx @ Wo + bo
        float acc = 0.f;
        #pragma unroll
        for (int k4 = 0; k4 < 64; k4 += 4) {
            int kk = pair*64 + k4;
            float4 c4 = *(const float4*)&ctxa[kk];
            acc += c4.x*L::at(Wo,(long)kk*128+c)     + c4.y*L::at(Wo,(long)(kk+1)*128+c)
                 + c4.z*L::at(Wo,(long)(kk+2)*128+c) + c4.w*L::at(Wo,(long)(kk+3)*128+c);
        }
        p1k[pair*128 + c] = acc;
    }
    __syncthreads();
    if (tid < 128) aoa[tid] = p1k[tid] + p1k[128+tid] + L::at(bo, tid);
    __syncthreads();
    {   // y2 = ao @ Wco + bco
        float acc0 = 0.f, acc1 = 0.f;
        #pragma unroll
        for (int k = 0; k < 128; k += 4) {
            float4 a4 = *(const float4*)&aoa[k];
            acc0 += a4.x*L::at(Wco,(long)k*512+tid)     + a4.y*L::at(Wco,(long)(k+1)*512+tid)
                  + a4.z*L::at(Wco,(long)(k+2)*512+tid) + a4.w*L::at(Wco,(long)(k+3)*512+tid);
            acc1 += a4.x*L::at(Wco,(long)k*512+tid+256)     + a4.y*L::at(Wco,(long)(k+1)*512+tid+256)
                  + a4.z*L::at(Wco,(long)(k+2)*512+tid+256) + a4.w*L::at(Wco,(long)(k+3)*512+tid+256);
        }
        y2a[tid]     = acc0 + L::at(bco, tid);
        y2a[tid+256] = acc1 + L::at(bco, tid+256);
    }
    __syncthreads();
    for (int o = 0; o < 3; o++) {
        float p = y2a[tid]*L::at(Wout,(long)tid*3+o)
                + y2a[tid+256]*L::at(Wout,(long)(tid+256)*3+o);
        p1k[tid] = p; __syncthreads();
        for (int st = 128; st > 0; st >>= 1) {
            if (tid < st) p1k[tid] += p1k[tid+st];
            __syncthreads();
        }
        if (tid == 0) {
            float val = p1k[0] + L::at(bout, o);
            if (BF16) ((ushort_t*)out)[b*3+o] = f2bf(val);
            else      ((float*)out)[b*3+o] = val;
        }
        __syncthreads();
    }
}

__global__ __launch_bounds__(256) void kE(
    float* ws,
    const void* Wtok, const void* btok, const void* Wv, const void* bv,
    const void* Wiv, const void* biv, const void* Wo, const void* bo,
    const void* Wco, const void* bco, const void* Wout, const void* bout,
    void* out)
{
    __shared__ float sh[3332];
    __shared__ int shi[32];
    if (*(const int*)(ws + WS_FLAG))
        kE_impl<true >(blockIdx.x, threadIdx.x, ws, Wtok,btok,Wv,bv,Wiv,biv,
                       Wo,bo,Wco,bco,Wout,bout,out,sh,shi);
    else
        kE_impl<false>(blockIdx.x, threadIdx.x, ws, Wtok,btok,Wv,bv,Wiv,biv,
                       Wo,bo,Wco,bco,Wout,bout,out,sh,shi);
}

// ---------------------------------------------------------------------------
extern "C" void kernel_launch(void* const* d_in, const int* in_sizes, int n_in,
                              void* d_out, int out_size, void* d_ws, size_t ws_size,
                              hipStream_t stream)
{
    const void* features = d_in[0];
    const int*  batch_idx= (const int*)d_in[1];
    const void* y_t      = d_in[2];
    const int*  t        = (const int*)d_in[3];
    // d_in[4] = N_max (unused)
    const void *Wtok=d_in[5],  *btok=d_in[6];
    const void *Wt  =d_in[7],  *bt  =d_in[8];
    const void *Win =d_in[9],  *bin_=d_in[10];
    const void *Wq  =d_in[11], *bq  =d_in[12];
    const void *Wk  =d_in[13], *bk  =d_in[14];
    const void *Wv  =d_in[15], *bv  =d_in[16];
    const void *Wiq =d_in[17], *biq =d_in[18];
    const void *Wik =d_in[19], *bik =d_in[20];
    const void *Wiv =d_in[21], *biv =d_in[22];
    const void *Wo  =d_in[23], *bo  =d_in[24];
    const void *Wco =d_in[25], *bco =d_in[26];
    const void *Wout=d_in[27], *bout=d_in[28];

    int N = in_sizes[0] / CENC;   // 131072
    float* ws = (float*)d_ws;

    kA<<<NB, 256, 0, stream>>>((const ushort_t*)features, y_t, t,
        Wt, bt, Win, bin_, Wq, bq, Wiq, biq, Wtok, btok, Wk, bk, Wik, bik, ws);
    kF<<<N / 128, 256, 0, stream>>>(features, batch_idx, ws);
    kE<<<NB, 256, 0, stream>>>(ws, Wtok, btok, Wv, bv, Wiv, biv, Wo, bo,
                               Wco, bco, Wout, bout, d_out);
}

// Round 7
// 201.572 us; speedup vs baseline: 1.4576x; 1.0804x over previous
//
#include <hip/hip_runtime.h>
#include <hip/hip_bf16.h>

// SparseDiffusionModel on MI355X — dtype-adaptive (fp32 confirmed active).
//
// Algebra: everything between `features` and attention is affine in features;
// query is one token/batch:
//   score[i,h] = f_i . u[b,h] + cq[b,h],  u_h = Wtok@(Wk@(Wik[:,hblk]@q_h))/sqrt32
//   ctx_h = ((wbar_h@Wtok+btok)@Wv+bv)@Wiv[:,hblk]+biv, wbar = softmax-wtd mean.
//
// Round-6 postmortem: kF 55us @ VALUBusy 9%, ~7 lines in flight per wave —
// phase-1 thread-per-row SCALAR loads serialized into vmcnt batches at 20%
// occupancy. This round: kF only — 16-lane x 8-channel coalesced float4
// phase 1 (u in named float4 regs), lane=channel float2 phase 2, ~11 KB LDS,
// 4 blocks/CU. kA/kE unchanged from round 6.
//
// ws (floats): flag | cnt[64 i32] | slot[64*32 i32] | u[32768] | cq[256]
//   | l_ovf[256] | w_ovf[32768] | lpart[8192] | wpart[2048*512 bf16] ~1.35 MB

typedef unsigned short ushort_t;
typedef unsigned int uint_t;
typedef unsigned long long ull_t;

#define NB 64
#define CENC 128
#define HID 512
#define RSQRT32 0.17677669529663689f

#define WS_FLAG   0
#define WS_CNT    64
#define WS_SLOT   128
#define WS_U      2176
#define WS_CQ     34944
#define WS_LOVF   35200
#define WS_WOVF   35456
#define WS_LPART  68224
#define WS_WPART  76416

__device__ __forceinline__ float blo(uint_t u){ return __uint_as_float(u << 16); }
__device__ __forceinline__ float bhi(uint_t u){ return __uint_as_float(u & 0xffff0000u); }
__device__ __forceinline__ float bf2f(ushort_t h){ return __uint_as_float(((uint_t)h) << 16); }
__device__ __forceinline__ ushort_t f2bf(float f){
    uint_t u = __float_as_uint(f);
    u += 0x7fffu + ((u >> 16) & 1u);   // RNE
    return (ushort_t)(u >> 16);
}

template<bool BF16> struct Ld;
template<> struct Ld<true> {
    static __device__ __forceinline__ float at(const void* p, long i) {
        return __uint_as_float(((uint_t)((const ushort_t*)p)[i]) << 16);
    }
};
template<> struct Ld<false> {
    static __device__ __forceinline__ float at(const void* p, long i) {
        return ((const float*)p)[i];
    }
};

// dtype detection on first 4096 ushorts of features (see r2/r3 notes).
__device__ int detect_bf16(const ushort_t* f, int tid, int* sh2) {
    if (tid == 0) { sh2[0] = 0; sh2[1] = 0; }
    __syncthreads();
    int myb = 0, myz = 0;
    for (int i = tid; i < 4096; i += 256) {
        ushort_t v = f[i];
        if (((v >> 7) & 0xff) >= 140) myb = 1;
        if (!(i & 1) && v == 0) myz++;
    }
    if (myb) atomicOr(&sh2[0], 1);
    atomicAdd(&sh2[1], myz);
    __syncthreads();
    return (sh2[0] || sh2[1] > 1024) ? 0 : 1;   // 1 = true bf16
}

// ---------------------------------------------------------------------------
// kA: per batch (64 x 256) — unchanged from round 6.
template<bool BF16>
__device__ void kA_impl(int b, int tid,
    const void* y_t, const int* t,
    const void* Wt, const void* bt, const void* Win, const void* bin_,
    const void* Wq, const void* bq, const void* Wiq, const void* biq,
    const void* Wtok, const void* btok, const void* Wk, const void* bk,
    const void* Wik, const void* bik, float* ws, float* sh)
{
    using L = Ld<BF16>;
    float* emb = sh;            // 64
    float* y   = sh + 64;       // 512
    float* p2  = sh + 576;      // 256
    float* q0  = sh + 832;      // 128
    float* qL  = sh + 960;      // 128
    float* tb  = sh + 1088;     // 128
    float* t1a = sh + 1216;     // 512
    float* t2a = sh + 1728;     // 512
    float* p1k = sh + 2240;     // 1024
    float* u_out  = ws + WS_U;
    float* cq_out = ws + WS_CQ;

    const int c = tid & 127, pair = tid >> 7;

    for (int i = tid; i < 512; i += 256) ws[WS_WOVF + b*512 + i] = 0.f;
    if (tid < 4) ws[WS_LOVF + b*4 + tid] = 0.f;
    if (tid == 0) ((int*)ws)[WS_CNT + b] = 0;

    if (tid < 32) {
        float fr = __expf(-(float)tid * 0.28782313662425576f); // ln(1e4)/32
        float arg = (float)t[b] * fr;
        emb[tid]      = sinf(arg);
        emb[tid + 32] = cosf(arg);
    }
    __syncthreads();

    float yt0 = L::at(y_t, b*3+0), yt1 = L::at(y_t, b*3+1), yt2 = L::at(y_t, b*3+2);
    #pragma unroll
    for (int rep = 0; rep < 2; rep++) {
        int o = tid + rep*256;
        float acc = L::at(bt, o);
        #pragma unroll
        for (int k = 0; k < 64; k++) acc += emb[k] * L::at(Wt, (long)k*512 + o);
        acc = fmaxf(acc, 0.f);
        y[o] = acc + L::at(bin_, o) + yt0*L::at(Win, o) + yt1*L::at(Win, 512+o)
             + yt2*L::at(Win, 1024+o);
    }
    __syncthreads();
    {   // q0 = y @ Wq + bq
        float acc = 0.f;
        #pragma unroll
        for (int k4 = 0; k4 < 256; k4 += 4) {
            int kk = pair*256 + k4;
            float4 y4 = *(const float4*)&y[kk];
            acc += y4.x*L::at(Wq,(long)kk*128+c)     + y4.y*L::at(Wq,(long)(kk+1)*128+c)
                 + y4.z*L::at(Wq,(long)(kk+2)*128+c) + y4.w*L::at(Wq,(long)(kk+3)*128+c);
        }
        p2[pair*128 + c] = acc;
    }
    __syncthreads();
    if (tid < 128) q0[tid] = p2[tid] + p2[128+tid] + L::at(bq, tid);
    __syncthreads();
    {   // qL = q0 @ Wiq + biq
        float acc = 0.f;
        #pragma unroll
        for (int k4 = 0; k4 < 64; k4 += 4) {
            int kk = pair*64 + k4;
            float4 q4 = *(const float4*)&q0[kk];
            acc += q4.x*L::at(Wiq,(long)kk*128+c)     + q4.y*L::at(Wiq,(long)(kk+1)*128+c)
                 + q4.z*L::at(Wiq,(long)(kk+2)*128+c) + q4.w*L::at(Wiq,(long)(kk+3)*128+c);
        }
        p2[pair*128 + c] = acc;
    }
    __syncthreads();
    if (tid < 128) qL[tid] = p2[tid] + p2[128+tid] + L::at(biq, tid);
    __syncthreads();
    {   // tb = btok @ Wk + bk
        float acc = 0.f;
        #pragma unroll
        for (int k4 = 0; k4 < 64; k4 += 4) {
            int kk = pair*64 + k4;
            acc += L::at(btok,kk)  *L::at(Wk,(long)kk*128+c)
                 + L::at(btok,kk+1)*L::at(Wk,(long)(kk+1)*128+c)
                 + L::at(btok,kk+2)*L::at(Wk,(long)(kk+2)*128+c)
                 + L::at(btok,kk+3)*L::at(Wk,(long)(kk+3)*128+c);
        }
        p2[pair*128 + c] = acc;
    }
    __syncthreads();
    if (tid < 128) tb[tid] = p2[tid] + p2[128+tid] + L::at(bk, tid);
    __syncthreads();
    {   // t1[h][c] = Wik[c, h*32+j] . qL_h   (heads folded)
        float a0=0.f, a1=0.f, a2=0.f, a3=0.f;
        #pragma unroll
        for (int j = 0; j < 16; j++) {
            int jj = pair*16 + j;
            a0 += L::at(Wik,(long)c*128 +  0 + jj) * qL[ 0 + jj];
            a1 += L::at(Wik,(long)c*128 + 32 + jj) * qL[32 + jj];
            a2 += L::at(Wik,(long)c*128 + 64 + jj) * qL[64 + jj];
            a3 += L::at(Wik,(long)c*128 + 96 + jj) * qL[96 + jj];
        }
        p1k[pair*512 +   0 + c] = a0; p1k[pair*512 + 128 + c] = a1;
        p1k[pair*512 + 256 + c] = a2; p1k[pair*512 + 384 + c] = a3;
    }
    __syncthreads();
    t1a[tid]     = p1k[tid]     + p1k[512+tid];
    t1a[tid+256] = p1k[tid+256] + p1k[768+tid];
    __syncthreads();
    {   // cq per head: wave h
        int hw = tid >> 6, lam = tid & 63;
        float r = tb[lam]*t1a[hw*128+lam] + tb[lam+64]*t1a[hw*128+64+lam];
        if (lam < 32) r += L::at(bik, hw*32+lam) * qL[hw*32+lam];
        #pragma unroll
        for (int mm = 1; mm < 64; mm <<= 1) r += __shfl_xor(r, mm, 64);
        if (lam == 0) cq_out[b*4 + hw] = r * RSQRT32;
    }
    {   // t2[h][c] = Wk[c,:] . t1[h]
        float a0=0.f, a1=0.f, a2=0.f, a3=0.f;
        #pragma unroll
        for (int k4 = 0; k4 < 64; k4 += 4) {
            int kk = pair*64 + k4;
            float wa = L::at(Wk,(long)c*128+kk),   wbv = L::at(Wk,(long)c*128+kk+1);
            float wc = L::at(Wk,(long)c*128+kk+2), wd  = L::at(Wk,(long)c*128+kk+3);
            float4 t0 = *(const float4*)&t1a[kk],     t1v = *(const float4*)&t1a[128+kk];
            float4 t2v = *(const float4*)&t1a[256+kk], t3v = *(const float4*)&t1a[384+kk];
            a0 += wa*t0.x + wbv*t0.y + wc*t0.z + wd*t0.w;
            a1 += wa*t1v.x + wbv*t1v.y + wc*t1v.z + wd*t1v.w;
            a2 += wa*t2v.x + wbv*t2v.y + wc*t2v.z + wd*t2v.w;
            a3 += wa*t3v.x + wbv*t3v.y + wc*t3v.z + wd*t3v.w;
        }
        p1k[pair*512 +   0 + c] = a0; p1k[pair*512 + 128 + c] = a1;
        p1k[pair*512 + 256 + c] = a2; p1k[pair*512 + 384 + c] = a3;
    }
    __syncthreads();
    t2a[tid]     = p1k[tid]     + p1k[512+tid];
    t2a[tid+256] = p1k[tid+256] + p1k[768+tid];
    __syncthreads();
    {   // u[h][c] = Wtok[c,:] . t2[h]
        float a0=0.f, a1=0.f, a2=0.f, a3=0.f;
        #pragma unroll
        for (int k4 = 0; k4 < 64; k4 += 4) {
            int kk = pair*64 + k4;
            float wa = L::at(Wtok,(long)c*128+kk),   wbv = L::at(Wtok,(long)c*128+kk+1);
            float wc = L::at(Wtok,(long)c*128+kk+2), wd  = L::at(Wtok,(long)c*128+kk+3);
            float4 t0 = *(const float4*)&t2a[kk],     t1v = *(const float4*)&t2a[128+kk];
            float4 t2v = *(const float4*)&t2a[256+kk], t3v = *(const float4*)&t2a[384+kk];
            a0 += wa*t0.x + wbv*t0.y + wc*t0.z + wd*t0.w;
            a1 += wa*t1v.x + wbv*t1v.y + wc*t1v.z + wd*t1v.w;
            a2 += wa*t2v.x + wbv*t2v.y + wc*t2v.z + wd*t2v.w;
            a3 += wa*t3v.x + wbv*t3v.y + wc*t3v.z + wd*t3v.w;
        }
        p1k[pair*512 +   0 + c] = a0; p1k[pair*512 + 128 + c] = a1;
        p1k[pair*512 + 256 + c] = a2; p1k[pair*512 + 384 + c] = a3;
    }
    __syncthreads();
    u_out[b*512 + tid]     = (p1k[tid]     + p1k[512+tid]) * RSQRT32;
    u_out[b*512 + tid+256] = (p1k[tid+256] + p1k[768+tid]) * RSQRT32;
}

__global__ __launch_bounds__(256) void kA(
    const ushort_t* __restrict__ fraw,
    const void* y_t, const int* t,
    const void* Wt, const void* bt, const void* Win, const void* bin_,
    const void* Wq, const void* bq, const void* Wiq, const void* biq,
    const void* Wtok, const void* btok, const void* Wk, const void* bk,
    const void* Wik, const void* bik, float* ws)
{
    __shared__ int sh2[2];
    __shared__ float sh[3264];
    int flag = detect_bf16(fraw, threadIdx.x, sh2);
    if (blockIdx.x == 0 && threadIdx.x == 0) *(int*)(ws + WS_FLAG) = flag;
    if (flag) kA_impl<true >(blockIdx.x, threadIdx.x, y_t,t,Wt,bt,Win,bin_,Wq,bq,
                             Wiq,biq,Wtok,btok,Wk,bk,Wik,bik, ws, sh);
    else      kA_impl<false>(blockIdx.x, threadIdx.x, y_t,t,Wt,bt,Win,bin_,Wq,bq,
                             Wiq,biq,Wtok,btok,Wk,bk,Wik,bik, ws, sh);
}

// ---------------------------------------------------------------------------
// kF: streaming pass (1024 x 256), tile-less, atomic-free, fully coalesced.
// Phase 1: 16 groups x 16 lanes; lane qq owns channels [8qq,8qq+8); u in 8
//   named float4 regs; two float4 (or one uint4) f-loads per token — per
//   instruction a wave touches 2 KB contiguous; shfl_xor(16) tree; all-lane
//   redundant exp; lane0 wave l-sum via shfl_xor(16,32).
// Phase 2: lane = channel-pair (float2 loads, 512B/instr, L1/L2-hot re-read),
//   4-way token split across waves; pp LDS combine; slot-list bf16 partials.
__device__ __forceinline__ float dot8(float4 fa, float4 fb, float4 ua, float4 ub) {
    return fa.x*ua.x + fa.y*ua.y + fa.z*ua.z + fa.w*ua.w
         + fb.x*ub.x + fb.y*ub.y + fb.z*ub.z + fb.w*ub.w;
}

template<bool BF16>
__device__ void kF_impl(const void* F, const int* __restrict__ batch_idx,
                        float* __restrict__ ws, int blk)
{
    __shared__ float eL[512];         // [tok][4 heads]
    __shared__ float pp[4*520];       // 4 token-groups x 512 outs (+pad)
    __shared__ float red[16];         // [wave][4 heads]
    __shared__ int lb[128];
    __shared__ int starts[129];
    __shared__ ull_t smask[2];
    __shared__ int nsegs;
    __shared__ int segslot[2];

    const int base = blk * 128;
    const int tau = threadIdx.x;
    const float* u   = ws + WS_U;
    const float* cqg = ws + WS_CQ;
    int* cnt      = (int*)ws + WS_CNT;
    int* slotlist = (int*)ws + WS_SLOT;
    float* l_ovf  = ws + WS_LOVF;
    float* w_ovf  = ws + WS_WOVF;
    float* lpart  = ws + WS_LPART;
    ushort_t* wpart = (ushort_t*)(ws + WS_WPART);

    if (tau < 128) lb[tau] = batch_idx[base + tau];
    __syncthreads();
    bool isstart = (tau < 128) && (tau == 0 || lb[tau] != lb[tau-1]);
    ull_t m = __ballot(isstart);
    const int wv = tau >> 6, lane = tau & 63;
    if (wv < 2 && lane == 0) smask[wv] = m;
    __syncthreads();
    if (isstart) {
        int rank = ((wv == 1) ? __popcll(smask[0]) : 0)
                 + __popcll(m & ((1ull << lane) - 1ull));
        starts[rank] = tau;
    }
    if (tau == 0) nsegs = __popcll(smask[0]) + __popcll(smask[1]);
    __syncthreads();
    const int nseg = nsegs;
    if (tau < 2) {
        int ss = -1;
        if (tau < nseg) {
            int bb = lb[starts[tau]];
            int idx = atomicAdd(&cnt[bb], 1);
            if (idx < 32) { slotlist[bb*32 + idx] = blk*2 + tau; ss = blk*2 + tau; }
        }
        segslot[tau] = ss;
    }
    __syncthreads();

    const int qq = tau & 15, grp = tau >> 4;       // phase 1
    const int cp = tau & 63, grp4 = tau >> 6;      // phase 2

    for (int s = 0; s < nseg; s++) {
        const int lo = starts[s];
        const int hi = (s + 1 < nseg) ? starts[s+1] : 128;
        const int b  = lb[lo];
        const int slot = (s < 2) ? segslot[s] : -1;

        // ---- phase 1 ----
        const float* ub = u + b*512 + qq*8;
        float4 u0a = *(const float4*)(ub + 0),   u0b = *(const float4*)(ub + 4);
        float4 u1a = *(const float4*)(ub + 128), u1b = *(const float4*)(ub + 132);
        float4 u2a = *(const float4*)(ub + 256), u2b = *(const float4*)(ub + 260);
        float4 u3a = *(const float4*)(ub + 384), u3b = *(const float4*)(ub + 388);
        float4 cqr = *(const float4*)(cqg + b*4);

        float l0=0.f, l1=0.f, l2=0.f, l3=0.f;
        #pragma unroll 2
        for (int tok = lo + grp; tok < hi; tok += 16) {
            float4 fa, fb;
            if (BF16) {
                uint4 v = *(const uint4*)((const ushort_t*)F + ((long)(base+tok) << 7) + (qq << 3));
                fa.x=blo(v.x); fa.y=bhi(v.x); fa.z=blo(v.y); fa.w=bhi(v.y);
                fb.x=blo(v.z); fb.y=bhi(v.z); fb.z=blo(v.w); fb.w=bhi(v.w);
            } else {
                const float4* fp = (const float4*)((const float*)F + ((long)(base+tok) << 7) + (qq << 3));
                fa = fp[0]; fb = fp[1];
            }
            float p0 = dot8(fa, fb, u0a, u0b);
            float p1 = dot8(fa, fb, u1a, u1b);
            float p2 = dot8(fa, fb, u2a, u2b);
            float p3 = dot8(fa, fb, u3a, u3b);
            #pragma unroll
            for (int mm = 1; mm < 16; mm <<= 1) {
                p0 += __shfl_xor(p0, mm, 16);
                p1 += __shfl_xor(p1, mm, 16);
                p2 += __shfl_xor(p2, mm, 16);
                p3 += __shfl_xor(p3, mm, 16);
            }
            // all 16 lanes have the dots: redundant exp avoids a divergent branch
            float e0 = __expf(fminf(p0 + cqr.x, 30.f));
            float e1 = __expf(fminf(p1 + cqr.y, 30.f));
            float e2 = __expf(fminf(p2 + cqr.z, 30.f));
            float e3 = __expf(fminf(p3 + cqr.w, 30.f));
            if (qq == 0) *(float4*)&eL[tok*4] = make_float4(e0, e1, e2, e3);
            l0 += e0; l1 += e1; l2 += e2; l3 += e3;
        }
        // lacc duplicated across 16 lanes of each group; xor(16)+xor(32)
        // sums the wave's 4 groups (each counted once).
        l0 += __shfl_xor(l0, 16, 64); l1 += __shfl_xor(l1, 16, 64);
        l2 += __shfl_xor(l2, 16, 64); l3 += __shfl_xor(l3, 16, 64);
        l0 += __shfl_xor(l0, 32, 64); l1 += __shfl_xor(l1, 32, 64);
        l2 += __shfl_xor(l2, 32, 64); l3 += __shfl_xor(l3, 32, 64);
        if (lane == 0) *(float4*)&red[wv*4] = make_float4(l0, l1, l2, l3);
        __syncthreads();   // eL + red ready

        if (tau < 4) {
            float ls = red[tau] + red[4+tau] + red[8+tau] + red[12+tau];
            if (slot >= 0) lpart[slot*4 + tau] = ls;
            else atomicAdd(&l_ovf[b*4 + tau], ls);
        }

        // ---- phase 2 ----
        float a00=0.f,a01=0.f,a10=0.f,a11=0.f,a20=0.f,a21=0.f,a30=0.f,a31=0.f;
        #pragma unroll 2
        for (int tk = lo + grp4; tk < hi; tk += 4) {
            float f0, f1;
            if (BF16) {
                uint_t v = *(const uint_t*)((const ushort_t*)F + ((long)(base+tk) << 7) + (cp << 1));
                f0 = blo(v); f1 = bhi(v);
            } else {
                float2 v = *(const float2*)((const float*)F + ((long)(base+tk) << 7) + (cp << 1));
                f0 = v.x; f1 = v.y;
            }
            float4 e = *(const float4*)&eL[tk*4];
            a00 += e.x*f0; a01 += e.x*f1;
            a10 += e.y*f0; a11 += e.y*f1;
            a20 += e.z*f0; a21 += e.z*f1;
            a30 += e.w*f0; a31 += e.w*f1;
        }
        {   // pp[grp4][h*128 + ch]
            float* pr = pp + grp4*520;
            *(float2*)&pr[  0 + 2*cp] = make_float2(a00, a01);
            *(float2*)&pr[128 + 2*cp] = make_float2(a10, a11);
            *(float2*)&pr[256 + 2*cp] = make_float2(a20, a21);
            *(float2*)&pr[384 + 2*cp] = make_float2(a30, a31);
        }
        __syncthreads();
        #pragma unroll
        for (int rep = 0; rep < 2; rep++) {
            int i = tau + rep*256;       // flat h*128+ch
            float v = pp[i] + pp[520 + i] + pp[1040 + i] + pp[1560 + i];
            if (slot >= 0) wpart[(long)slot*512 + i] = f2bf(v);
            else atomicAdd(&w_ovf[b*512 + i], v);
        }
        __syncthreads();   // eL/red/pp reuse next segment
    }
}

__global__ __launch_bounds__(256, 4) void kF(
    const void* __restrict__ features, const int* __restrict__ batch_idx,
    float* __restrict__ ws)
{
    if (*(const int*)(ws + WS_FLAG)) kF_impl<true >(features, batch_idx, ws, blockIdx.x);
    else                             kF_impl<false>(features, batch_idx, ws, blockIdx.x);
}

// ---------------------------------------------------------------------------
// kE: per batch (64 x 256) — unchanged from round 6.
template<bool BF16>
__device__ void kE_impl(int b, int tid, float* ws,
    const void* Wtok, const void* btok, const void* Wv, const void* bv,
    const void* Wiv, const void* biv, const void* Wo, const void* bo,
    const void* Wco, const void* bco, const void* Wout, const void* bout,
    void* out, float* sh, int* shi)
{
    using L = Ld<BF16>;
    float* wb   = sh;            // 512
    float* s1a  = sh + 512;      // 512
    float* s2a  = sh + 1024;     // 512
    float* ctxa = sh + 1536;     // 128
    float* aoa  = sh + 1664;     // 128
    float* y2a  = sh + 1792;     // 512
    float* p1k  = sh + 2304;     // 1024
    float* linv = sh + 3328;     // 4

    const int c = tid & 127, pair = tid >> 7;
    const int* cnti = (const int*)ws;
    const ushort_t* wpart = (const ushort_t*)(ws + WS_WPART);

    int n = cnti[WS_CNT + b]; if (n > 32) n = 32;
    if (tid < 32) shi[tid] = (tid < n) ? cnti[WS_SLOT + b*32 + tid] : 0;
    __syncthreads();

    float a0 = 0.f, a1 = 0.f, lac = 0.f;
    for (int i = 0; i < n; i++) {
        int s = shi[i];
        a0 += bf2f(wpart[(long)s*512 + tid]);
        a1 += bf2f(wpart[(long)s*512 + tid + 256]);
    }
    if (tid < 4) for (int i = 0; i < n; i++) lac += ws[WS_LPART + shi[i]*4 + tid];
    a0 += ws[WS_WOVF + b*512 + tid];
    a1 += ws[WS_WOVF + b*512 + tid + 256];
    if (tid < 4) {
        lac += ws[WS_LOVF + b*4 + tid];
        linv[tid] = (lac > 1e-30f) ? 1.f/lac : 0.f;
    }
    __syncthreads();
    wb[tid]     = a0 * linv[tid >> 7];
    wb[tid+256] = a1 * linv[(tid+256) >> 7];
    __syncthreads();

    {   // s1[h][c] = wbar_h @ Wtok[:,c]
        float b0=0.f,b1=0.f,b2=0.f,b3=0.f;
        #pragma unroll
        for (int k4 = 0; k4 < 64; k4 += 4) {
            int kk = pair*64 + k4;
            float wa = L::at(Wtok,(long)kk*128+c),     wbv = L::at(Wtok,(long)(kk+1)*128+c);
            float wc = L::at(Wtok,(long)(kk+2)*128+c), wd  = L::at(Wtok,(long)(kk+3)*128+c);
            float4 w0 = *(const float4*)&wb[kk],     w1 = *(const float4*)&wb[128+kk];
            float4 w2 = *(const float4*)&wb[256+kk], w3 = *(const float4*)&wb[384+kk];
            b0 += wa*w0.x + wbv*w0.y + wc*w0.z + wd*w0.w;
            b1 += wa*w1.x + wbv*w1.y + wc*w1.z + wd*w1.w;
            b2 += wa*w2.x + wbv*w2.y + wc*w2.z + wd*w2.w;
            b3 += wa*w3.x + wbv*w3.y + wc*w3.z + wd*w3.w;
        }
        p1k[pair*512 +   0 + c] = b0; p1k[pair*512 + 128 + c] = b1;
        p1k[pair*512 + 256 + c] = b2; p1k[pair*512 + 384 + c] = b3;
    }
    __syncthreads();
    s1a[tid]     = p1k[tid]     + p1k[512+tid]     + L::at(btok, tid & 127);
    s1a[tid+256] = p1k[tid+256] + p1k[768+tid]     + L::at(btok, (tid+256) & 127);
    __syncthreads();
    {   // s2[h][c] = s1_h @ Wv[:,c] + bv
        float b0=0.f,b1=0.f,b2=0.f,b3=0.f;
        #pragma unroll
        for (int k4 = 0; k4 < 64; k4 += 4) {
            int kk = pair*64 + k4;
            float wa = L::at(Wv,(long)kk*128+c),     wbv = L::at(Wv,(long)(kk+1)*128+c);
            float wc = L::at(Wv,(long)(kk+2)*128+c), wd  = L::at(Wv,(long)(kk+3)*128+c);
            float4 w0 = *(const float4*)&s1a[kk],     w1 = *(const float4*)&s1a[128+kk];
            float4 w2 = *(const float4*)&s1a[256+kk], w3 = *(const float4*)&s1a[384+kk];
            b0 += wa*w0.x + wbv*w0.y + wc*w0.z + wd*w0.w;
            b1 += wa*w1.x + wbv*w1.y + wc*w1.z + wd*w1.w;
            b2 += wa*w2.x + wbv*w2.y + wc*w2.z + wd*w2.w;
            b3 += wa*w3.x + wbv*w3.y + wc*w3.z + wd*w3.w;
        }
        p1k[pair*512 +   0 + c] = b0; p1k[pair*512 + 128 + c] = b1;
        p1k[pair*512 + 256 + c] = b2; p1k[pair*512 + 384 + c] = b3;
    }
    __syncthreads();
    s2a[tid]     = p1k[tid]     + p1k[512+tid] + L::at(bv, tid & 127);
    s2a[tid+256] = p1k[tid+256] + p1k[768+tid] + L::at(bv, (tid+256) & 127);
    __syncthreads();
    {   // ctx[o]= s2_h @ Wiv[:, o]
        int h = c >> 5;
        float acc = 0.f;
        #pragma unroll
        for (int k4 = 0; k4 < 64; k4 += 4) {
            int kk = pair*64 + k4;
            float4 s4 = *(const float4*)&s2a[h*128 + kk];
            acc += s4.x*L::at(Wiv,(long)kk*128+c)     + s4.y*L::at(Wiv,(long)(kk+1)*128+c)
                 + s4.z*L::at(Wiv,(long)(kk+2)*128+c) + s4.w*L::at(Wiv,(long)(kk+3)*128+c);
        }
        p1k[pair*128 + c] = acc;
    }
    __syncthreads();
    if (tid < 128) ctxa[tid] = p1k[tid] + p1k[128+tid] + L::at(biv, tid);
    __syncthreads();
    {   // ao = ctx @ Wo + bo
        float acc = 0.f;
        #pragma unroll
        for (int k4 = 0; k4 < 64; k4 += 4) {
            int kk = pair*64 + k4;
            float4 c4 = *(const float4*)&ctxa[kk];
            acc += c4.x*L::at(Wo,(long)kk*128+c)     + c4.y*L::at(Wo,(long)(kk+1)*128+c)
                 + c4.z*L::at(Wo,(long)(kk+2)*128+c) + c4.w*L::at(Wo,(long)(kk+3)*128+c);
        }
        p1k[pair*128 + c] = acc;
    }
    __syncthreads();
    if (tid < 128) aoa[tid] = p1k[tid] + p1k[128+tid] + L::at(bo, tid);
    __syncthreads();
    {   // y2 = ao @ Wco + bco
        float acc0 = 0.f, acc1 = 0.f;
        #pragma unroll
        for (int k = 0; k < 128; k += 4) {
            float4 a4 = *(const float4*)&aoa[k];
            acc0 += a4.x*L::at(Wco,(long)k*512+tid)     + a4.y*L::at(Wco,(long)(k+1)*512+tid)
                  + a4.z*L::at(Wco,(long)(k+2)*512+tid) + a4.w*L::at(Wco,(long)(k+3)*512+tid);
            acc1 += a4.x*L::at(Wco,(long)k*512+tid+256)     + a4.y*L::at(Wco,(long)(k+1)*512+tid+256)
                  + a4.z*L::at(Wco,(long)(k+2)*512+tid+256) + a4.w*L::at(Wco,(long)(k+3)*512+tid+256);
        }
        y2a[tid]     = acc0 + L::at(bco, tid);
        y2a[tid+256] = acc1 + L::at(bco, tid+256);
    }
    __syncthreads();
    for (int o = 0; o < 3; o++) {
        float p = y2a[tid]*L::at(Wout,(long)tid*3+o)
                + y2a[tid+256]*L::at(Wout,(long)(tid+256)*3+o);
        p1k[tid] = p; __syncthreads();
        for (int st = 128; st > 0; st >>= 1) {
            if (tid < st) p1k[tid] += p1k[tid+st];
            __syncthreads();
        }
        if (tid == 0) {
            float val = p1k[0] + L::at(bout, o);
            if (BF16) ((ushort_t*)out)[b*3+o] = f2bf(val);
            else      ((float*)out)[b*3+o] = val;
        }
        __syncthreads();
    }
}

__global__ __launch_bounds__(256) void kE(
    float* ws,
    const void* Wtok, const void* btok, const void* Wv, const void* bv,
    const void* Wiv, const void* biv, const void* Wo, const void* bo,
    const void* Wco, const void* bco, const void* Wout, const void* bout,
    void* out)
{
    __shared__ float sh[3332];
    __shared__ int shi[32];
    if (*(const int*)(ws + WS_FLAG))
        kE_impl<true >(blockIdx.x, threadIdx.x, ws, Wtok,btok,Wv,bv,Wiv,biv,
                       Wo,bo,Wco,bco,Wout,bout,out,sh,shi);
    else
        kE_impl<false>(blockIdx.x, threadIdx.x, ws, Wtok,btok,Wv,bv,Wiv,biv,
                       Wo,bo,Wco,bco,Wout,bout,out,sh,shi);
}

// ---------------------------------------------------------------------------
extern "C" void kernel_launch(void* const* d_in, const int* in_sizes, int n_in,
                              void* d_out, int out_size, void* d_ws, size_t ws_size,
                              hipStream_t stream)
{
    const void* features = d_in[0];
    const int*  batch_idx= (const int*)d_in[1];
    const void* y_t      = d_in[2];
    const int*  t        = (const int*)d_in[3];
    // d_in[4] = N_max (unused)
    const void *Wtok=d_in[5],  *btok=d_in[6];
    const void *Wt  =d_in[7],  *bt  =d_in[8];
    const void *Win =d_in[9],  *bin_=d_in[10];
    const void *Wq  =d_in[11], *bq  =d_in[12];
    const void *Wk  =d_in[13], *bk  =d_in[14];
    const void *Wv  =d_in[15], *bv  =d_in[16];
    const void *Wiq =d_in[17], *biq =d_in[18];
    const void *Wik =d_in[19], *bik =d_in[20];
    const void *Wiv =d_in[21], *biv =d_in[22];
    const void *Wo  =d_in[23], *bo  =d_in[24];
    const void *Wco =d_in[25], *bco =d_in[26];
    const void *Wout=d_in[27], *bout=d_in[28];

    int N = in_sizes[0] / CENC;   // 131072
    float* ws = (float*)d_ws;

    kA<<<NB, 256, 0, stream>>>((const ushort_t*)features, y_t, t,
        Wt, bt, Win, bin_, Wq, bq, Wiq, biq, Wtok, btok, Wk, bk, Wik, bik, ws);
    kF<<<N / 128, 256, 0, stream>>>(features, batch_idx, ws);
    kE<<<NB, 256, 0, stream>>>(ws, Wtok, btok, Wv, bv, Wiv, biv, Wo, bo,
                               Wco, bco, Wout, bout, d_out);
}

// Round 8
// 195.134 us; speedup vs baseline: 1.5057x; 1.0330x over previous
//
#include <hip/hip_runtime.h>
#include <hip/hip_bf16.h>

// SparseDiffusionModel on MI355X — dtype-adaptive (fp32 confirmed active).
//
// Algebra: everything between `features` and attention is affine in features;
// query is one token/batch:
//   score[i,h] = f_i . u[b,h] + cq[b,h],  u_h = Wtok@(Wk@(Wik[:,hblk]@q_h))/sqrt32
//   ctx_h = ((wbar_h@Wtok+btok)@Wv+bv)@Wiv[:,hblk]+biv, wbar = softmax-wtd mean.
//
// Round-7 postmortem: harness reset (268 MB ws poison + input restores) is a
// ~150-165us floor we cannot touch; kF ~40us of the controllable ~45us. kF's
// cost was the SECOND pass over features. This round fuses both phases: the
// redundant all-lane exp gives every lane e for its token, so the lane that
// loaded f immediately does acc[h] += e_h*f into 8 named float4 regs. One
// HBM pass, no eL, 2 barriers/segment only for the epilogue reduce.
//
// ws (floats): flag | cnt[64 i32] | slot[64*32 i32] | u[32768] | cq[256]
//   | l_ovf[256] | w_ovf[32768] | lpart[8192] | wpart[2048*512 bf16] ~1.35 MB

typedef unsigned short ushort_t;
typedef unsigned int uint_t;
typedef unsigned long long ull_t;

#define NB 64
#define CENC 128
#define HID 512
#define RSQRT32 0.17677669529663689f

#define WS_FLAG   0
#define WS_CNT    64
#define WS_SLOT   128
#define WS_U      2176
#define WS_CQ     34944
#define WS_LOVF   35200
#define WS_WOVF   35456
#define WS_LPART  68224
#define WS_WPART  76416

__device__ __forceinline__ float blo(uint_t u){ return __uint_as_float(u << 16); }
__device__ __forceinline__ float bhi(uint_t u){ return __uint_as_float(u & 0xffff0000u); }
__device__ __forceinline__ float bf2f(ushort_t h){ return __uint_as_float(((uint_t)h) << 16); }
__device__ __forceinline__ ushort_t f2bf(float f){
    uint_t u = __float_as_uint(f);
    u += 0x7fffu + ((u >> 16) & 1u);   // RNE
    return (ushort_t)(u >> 16);
}

template<bool BF16> struct Ld;
template<> struct Ld<true> {
    static __device__ __forceinline__ float at(const void* p, long i) {
        return __uint_as_float(((uint_t)((const ushort_t*)p)[i]) << 16);
    }
};
template<> struct Ld<false> {
    static __device__ __forceinline__ float at(const void* p, long i) {
        return ((const float*)p)[i];
    }
};

// dtype detection on first 4096 ushorts of features (see r2/r3 notes).
__device__ int detect_bf16(const ushort_t* f, int tid, int* sh2) {
    if (tid == 0) { sh2[0] = 0; sh2[1] = 0; }
    __syncthreads();
    int myb = 0, myz = 0;
    for (int i = tid; i < 4096; i += 256) {
        ushort_t v = f[i];
        if (((v >> 7) & 0xff) >= 140) myb = 1;
        if (!(i & 1) && v == 0) myz++;
    }
    if (myb) atomicOr(&sh2[0], 1);
    atomicAdd(&sh2[1], myz);
    __syncthreads();
    return (sh2[0] || sh2[1] > 1024) ? 0 : 1;   // 1 = true bf16
}

// ---------------------------------------------------------------------------
// kA: per batch (64 x 256) — unchanged from round 6/7.
template<bool BF16>
__device__ void kA_impl(int b, int tid,
    const void* y_t, const int* t,
    const void* Wt, const void* bt, const void* Win, const void* bin_,
    const void* Wq, const void* bq, const void* Wiq, const void* biq,
    const void* Wtok, const void* btok, const void* Wk, const void* bk,
    const void* Wik, const void* bik, float* ws, float* sh)
{
    using L = Ld<BF16>;
    float* emb = sh;            // 64
    float* y   = sh + 64;       // 512
    float* p2  = sh + 576;      // 256
    float* q0  = sh + 832;      // 128
    float* qL  = sh + 960;      // 128
    float* tb  = sh + 1088;     // 128
    float* t1a = sh + 1216;     // 512
    float* t2a = sh + 1728;     // 512
    float* p1k = sh + 2240;     // 1024
    float* u_out  = ws + WS_U;
    float* cq_out = ws + WS_CQ;

    const int c = tid & 127, pair = tid >> 7;

    for (int i = tid; i < 512; i += 256) ws[WS_WOVF + b*512 + i] = 0.f;
    if (tid < 4) ws[WS_LOVF + b*4 + tid] = 0.f;
    if (tid == 0) ((int*)ws)[WS_CNT + b] = 0;

    if (tid < 32) {
        float fr = __expf(-(float)tid * 0.28782313662425576f); // ln(1e4)/32
        float arg = (float)t[b] * fr;
        emb[tid]      = sinf(arg);
        emb[tid + 32] = cosf(arg);
    }
    __syncthreads();

    float yt0 = L::at(y_t, b*3+0), yt1 = L::at(y_t, b*3+1), yt2 = L::at(y_t, b*3+2);
    #pragma unroll
    for (int rep = 0; rep < 2; rep++) {
        int o = tid + rep*256;
        float acc = L::at(bt, o);
        #pragma unroll
        for (int k = 0; k < 64; k++) acc += emb[k] * L::at(Wt, (long)k*512 + o);
        acc = fmaxf(acc, 0.f);
        y[o] = acc + L::at(bin_, o) + yt0*L::at(Win, o) + yt1*L::at(Win, 512+o)
             + yt2*L::at(Win, 1024+o);
    }
    __syncthreads();
    {   // q0 = y @ Wq + bq
        float acc = 0.f;
        #pragma unroll
        for (int k4 = 0; k4 < 256; k4 += 4) {
            int kk = pair*256 + k4;
            float4 y4 = *(const float4*)&y[kk];
            acc += y4.x*L::at(Wq,(long)kk*128+c)     + y4.y*L::at(Wq,(long)(kk+1)*128+c)
                 + y4.z*L::at(Wq,(long)(kk+2)*128+c) + y4.w*L::at(Wq,(long)(kk+3)*128+c);
        }
        p2[pair*128 + c] = acc;
    }
    __syncthreads();
    if (tid < 128) q0[tid] = p2[tid] + p2[128+tid] + L::at(bq, tid);
    __syncthreads();
    {   // qL = q0 @ Wiq + biq
        float acc = 0.f;
        #pragma unroll
        for (int k4 = 0; k4 < 64; k4 += 4) {
            int kk = pair*64 + k4;
            float4 q4 = *(const float4*)&q0[kk];
            acc += q4.x*L::at(Wiq,(long)kk*128+c)     + q4.y*L::at(Wiq,(long)(kk+1)*128+c)
                 + q4.z*L::at(Wiq,(long)(kk+2)*128+c) + q4.w*L::at(Wiq,(long)(kk+3)*128+c);
        }
        p2[pair*128 + c] = acc;
    }
    __syncthreads();
    if (tid < 128) qL[tid] = p2[tid] + p2[128+tid] + L::at(biq, tid);
    __syncthreads();
    {   // tb = btok @ Wk + bk
        float acc = 0.f;
        #pragma unroll
        for (int k4 = 0; k4 < 64; k4 += 4) {
            int kk = pair*64 + k4;
            acc += L::at(btok,kk)  *L::at(Wk,(long)kk*128+c)
                 + L::at(btok,kk+1)*L::at(Wk,(long)(kk+1)*128+c)
                 + L::at(btok,kk+2)*L::at(Wk,(long)(kk+2)*128+c)
                 + L::at(btok,kk+3)*L::at(Wk,(long)(kk+3)*128+c);
        }
        p2[pair*128 + c] = acc;
    }
    __syncthreads();
    if (tid < 128) tb[tid] = p2[tid] + p2[128+tid] + L::at(bk, tid);
    __syncthreads();
    {   // t1[h][c] = Wik[c, h*32+j] . qL_h
        float a0=0.f, a1=0.f, a2=0.f, a3=0.f;
        #pragma unroll
        for (int j = 0; j < 16; j++) {
            int jj = pair*16 + j;
            a0 += L::at(Wik,(long)c*128 +  0 + jj) * qL[ 0 + jj];
            a1 += L::at(Wik,(long)c*128 + 32 + jj) * qL[32 + jj];
            a2 += L::at(Wik,(long)c*128 + 64 + jj) * qL[64 + jj];
            a3 += L::at(Wik,(long)c*128 + 96 + jj) * qL[96 + jj];
        }
        p1k[pair*512 +   0 + c] = a0; p1k[pair*512 + 128 + c] = a1;
        p1k[pair*512 + 256 + c] = a2; p1k[pair*512 + 384 + c] = a3;
    }
    __syncthreads();
    t1a[tid]     = p1k[tid]     + p1k[512+tid];
    t1a[tid+256] = p1k[tid+256] + p1k[768+tid];
    __syncthreads();
    {   // cq per head: wave h
        int hw = tid >> 6, lam = tid & 63;
        float r = tb[lam]*t1a[hw*128+lam] + tb[lam+64]*t1a[hw*128+64+lam];
        if (lam < 32) r += L::at(bik, hw*32+lam) * qL[hw*32+lam];
        #pragma unroll
        for (int mm = 1; mm < 64; mm <<= 1) r += __shfl_xor(r, mm, 64);
        if (lam == 0) cq_out[b*4 + hw] = r * RSQRT32;
    }
    {   // t2[h][c] = Wk[c,:] . t1[h]
        float a0=0.f, a1=0.f, a2=0.f, a3=0.f;
        #pragma unroll
        for (int k4 = 0; k4 < 64; k4 += 4) {
            int kk = pair*64 + k4;
            float wa = L::at(Wk,(long)c*128+kk),   wbv = L::at(Wk,(long)c*128+kk+1);
            float wc = L::at(Wk,(long)c*128+kk+2), wd  = L::at(Wk,(long)c*128+kk+3);
            float4 t0 = *(const float4*)&t1a[kk],     t1v = *(const float4*)&t1a[128+kk];
            float4 t2v = *(const float4*)&t1a[256+kk], t3v = *(const float4*)&t1a[384+kk];
            a0 += wa*t0.x + wbv*t0.y + wc*t0.z + wd*t0.w;
            a1 += wa*t1v.x + wbv*t1v.y + wc*t1v.z + wd*t1v.w;
            a2 += wa*t2v.x + wbv*t2v.y + wc*t2v.z + wd*t2v.w;
            a3 += wa*t3v.x + wbv*t3v.y + wc*t3v.z + wd*t3v.w;
        }
        p1k[pair*512 +   0 + c] = a0; p1k[pair*512 + 128 + c] = a1;
        p1k[pair*512 + 256 + c] = a2; p1k[pair*512 + 384 + c] = a3;
    }
    __syncthreads();
    t2a[tid]     = p1k[tid]     + p1k[512+tid];
    t2a[tid+256] = p1k[tid+256] + p1k[768+tid];
    __syncthreads();
    {   // u[h][c] = Wtok[c,:] . t2[h]
        float a0=0.f, a1=0.f, a2=0.f, a3=0.f;
        #pragma unroll
        for (int k4 = 0; k4 < 64; k4 += 4) {
            int kk = pair*64 + k4;
            float wa = L::at(Wtok,(long)c*128+kk),   wbv = L::at(Wtok,(long)c*128+kk+1);
            float wc = L::at(Wtok,(long)c*128+kk+2), wd  = L::at(Wtok,(long)c*128+kk+3);
            float4 t0 = *(const float4*)&t2a[kk],     t1v = *(const float4*)&t2a[128+kk];
            float4 t2v = *(const float4*)&t2a[256+kk], t3v = *(const float4*)&t2a[384+kk];
            a0 += wa*t0.x + wbv*t0.y + wc*t0.z + wd*t0.w;
            a1 += wa*t1v.x + wbv*t1v.y + wc*t1v.z + wd*t1v.w;
            a2 += wa*t2v.x + wbv*t2v.y + wc*t2v.z + wd*t2v.w;
            a3 += wa*t3v.x + wbv*t3v.y + wc*t3v.z + wd*t3v.w;
        }
        p1k[pair*512 +   0 + c] = a0; p1k[pair*512 + 128 + c] = a1;
        p1k[pair*512 + 256 + c] = a2; p1k[pair*512 + 384 + c] = a3;
    }
    __syncthreads();
    u_out[b*512 + tid]     = (p1k[tid]     + p1k[512+tid]) * RSQRT32;
    u_out[b*512 + tid+256] = (p1k[tid+256] + p1k[768+tid]) * RSQRT32;
}

__global__ __launch_bounds__(256) void kA(
    const ushort_t* __restrict__ fraw,
    const void* y_t, const int* t,
    const void* Wt, const void* bt, const void* Win, const void* bin_,
    const void* Wq, const void* bq, const void* Wiq, const void* biq,
    const void* Wtok, const void* btok, const void* Wk, const void* bk,
    const void* Wik, const void* bik, float* ws)
{
    __shared__ int sh2[2];
    __shared__ float sh[3264];
    int flag = detect_bf16(fraw, threadIdx.x, sh2);
    if (blockIdx.x == 0 && threadIdx.x == 0) *(int*)(ws + WS_FLAG) = flag;
    if (flag) kA_impl<true >(blockIdx.x, threadIdx.x, y_t,t,Wt,bt,Win,bin_,Wq,bq,
                             Wiq,biq,Wtok,btok,Wk,bk,Wik,bik, ws, sh);
    else      kA_impl<false>(blockIdx.x, threadIdx.x, y_t,t,Wt,bt,Win,bin_,Wq,bq,
                             Wiq,biq,Wtok,btok,Wk,bk,Wik,bik, ws, sh);
}

// ---------------------------------------------------------------------------
// kF: SINGLE-PASS streaming kernel (1024 x 256), atomic-free (slot lists).
// 16 groups x 16 lanes; lane qq owns channels [8qq,8qq+8); per token:
// coalesced 32B f-load, dot vs u (8 named float4), shfl_xor(16) score tree,
// all-lane exp, THEN acc[h] += e_h*f in 8 named float4 accumulators.
// Epilogue per segment: shfl_xor(16/32) group combine + 8KB LDS wave combine.
__device__ __forceinline__ float dot8(float4 fa, float4 fb, float4 ua, float4 ub) {
    return fa.x*ua.x + fa.y*ua.y + fa.z*ua.z + fa.w*ua.w
         + fb.x*ub.x + fb.y*ub.y + fb.z*ub.z + fb.w*ub.w;
}
__device__ __forceinline__ void f4fma(float4& a, float e, float4 f) {
    a.x += e*f.x; a.y += e*f.y; a.z += e*f.z; a.w += e*f.w;
}
__device__ __forceinline__ void f4xr(float4& v, int m) {
    v.x += __shfl_xor(v.x, m, 64); v.y += __shfl_xor(v.y, m, 64);
    v.z += __shfl_xor(v.z, m, 64); v.w += __shfl_xor(v.w, m, 64);
}

template<bool BF16>
__device__ void kF_impl(const void* F, const int* __restrict__ batch_idx,
                        float* __restrict__ ws, int blk)
{
    __shared__ float ppw[4*512];      // per-wave combined w partials
    __shared__ float red[16];         // [wave][4 heads] l partials
    __shared__ int lb[128];
    __shared__ int starts[129];
    __shared__ ull_t smask[2];
    __shared__ int nsegs;
    __shared__ int segslot[2];

    const int base = blk * 128;
    const int tau = threadIdx.x;
    const float* u   = ws + WS_U;
    const float* cqg = ws + WS_CQ;
    int* cnt      = (int*)ws + WS_CNT;
    int* slotlist = (int*)ws + WS_SLOT;
    float* l_ovf  = ws + WS_LOVF;
    float* w_ovf  = ws + WS_WOVF;
    float* lpart  = ws + WS_LPART;
    ushort_t* wpart = (ushort_t*)(ws + WS_WPART);

    if (tau < 128) lb[tau] = batch_idx[base + tau];
    __syncthreads();
    bool isstart = (tau < 128) && (tau == 0 || lb[tau] != lb[tau-1]);
    ull_t m = __ballot(isstart);
    const int wv = tau >> 6, lane = tau & 63;
    if (wv < 2 && lane == 0) smask[wv] = m;
    __syncthreads();
    if (isstart) {
        int rank = ((wv == 1) ? __popcll(smask[0]) : 0)
                 + __popcll(m & ((1ull << lane) - 1ull));
        starts[rank] = tau;
    }
    if (tau == 0) nsegs = __popcll(smask[0]) + __popcll(smask[1]);
    __syncthreads();
    const int nseg = nsegs;
    if (tau < 2) {
        int ss = -1;
        if (tau < nseg) {
            int bb = lb[starts[tau]];
            int idx = atomicAdd(&cnt[bb], 1);
            if (idx < 32) { slotlist[bb*32 + idx] = blk*2 + tau; ss = blk*2 + tau; }
        }
        segslot[tau] = ss;
    }
    __syncthreads();

    const int qq = tau & 15, grp = tau >> 4;   // grp in block; in-wave grp = bits 4-5

    for (int s = 0; s < nseg; s++) {
        const int lo = starts[s];
        const int hi = (s + 1 < nseg) ? starts[s+1] : 128;
        const int b  = lb[lo];
        const int slot = (s < 2) ? segslot[s] : -1;

        const float* ub = u + b*512 + qq*8;
        float4 u0a = *(const float4*)(ub + 0),   u0b = *(const float4*)(ub + 4);
        float4 u1a = *(const float4*)(ub + 128), u1b = *(const float4*)(ub + 132);
        float4 u2a = *(const float4*)(ub + 256), u2b = *(const float4*)(ub + 260);
        float4 u3a = *(const float4*)(ub + 384), u3b = *(const float4*)(ub + 388);
        float4 cqr = *(const float4*)(cqg + b*4);

        float4 zz = make_float4(0.f, 0.f, 0.f, 0.f);
        float4 a0a=zz,a0b=zz,a1a=zz,a1b=zz,a2a=zz,a2b=zz,a3a=zz,a3b=zz;
        float l0=0.f, l1=0.f, l2=0.f, l3=0.f;

        #pragma unroll 2
        for (int tok = lo + grp; tok < hi; tok += 16) {
            float4 fa, fb;
            if (BF16) {
                uint4 v = *(const uint4*)((const ushort_t*)F + ((long)(base+tok) << 7) + (qq << 3));
                fa.x=blo(v.x); fa.y=bhi(v.x); fa.z=blo(v.y); fa.w=bhi(v.y);
                fb.x=blo(v.z); fb.y=bhi(v.z); fb.z=blo(v.w); fb.w=bhi(v.w);
            } else {
                const float4* fp = (const float4*)((const float*)F + ((long)(base+tok) << 7) + (qq << 3));
                fa = fp[0]; fb = fp[1];
            }
            float p0 = dot8(fa, fb, u0a, u0b);
            float p1 = dot8(fa, fb, u1a, u1b);
            float p2 = dot8(fa, fb, u2a, u2b);
            float p3 = dot8(fa, fb, u3a, u3b);
            #pragma unroll
            for (int mm = 1; mm < 16; mm <<= 1) {
                p0 += __shfl_xor(p0, mm, 16);
                p1 += __shfl_xor(p1, mm, 16);
                p2 += __shfl_xor(p2, mm, 16);
                p3 += __shfl_xor(p3, mm, 16);
            }
            // every lane of the 16-group now holds the token's 4 scores
            float e0 = __expf(fminf(p0 + cqr.x, 30.f));
            float e1 = __expf(fminf(p1 + cqr.y, 30.f));
            float e2 = __expf(fminf(p2 + cqr.z, 30.f));
            float e3 = __expf(fminf(p3 + cqr.w, 30.f));
            l0 += e0; l1 += e1; l2 += e2; l3 += e3;
            f4fma(a0a, e0, fa); f4fma(a0b, e0, fb);
            f4fma(a1a, e1, fa); f4fma(a1b, e1, fb);
            f4fma(a2a, e2, fa); f4fma(a2b, e2, fb);
            f4fma(a3a, e3, fa); f4fma(a3b, e3, fb);
        }

        // l: identical across each group's 16 lanes; xor(16)+xor(32) sums the
        // wave's 4 groups (each counted once).
        l0 += __shfl_xor(l0, 16, 64); l1 += __shfl_xor(l1, 16, 64);
        l2 += __shfl_xor(l2, 16, 64); l3 += __shfl_xor(l3, 16, 64);
        l0 += __shfl_xor(l0, 32, 64); l1 += __shfl_xor(l1, 32, 64);
        l2 += __shfl_xor(l2, 32, 64); l3 += __shfl_xor(l3, 32, 64);
        if (lane == 0) *(float4*)&red[wv*4] = make_float4(l0, l1, l2, l3);

        // acc: combine the wave's 4 groups (same channel slice per qq).
        f4xr(a0a,16); f4xr(a0b,16); f4xr(a1a,16); f4xr(a1b,16);
        f4xr(a2a,16); f4xr(a2b,16); f4xr(a3a,16); f4xr(a3b,16);
        f4xr(a0a,32); f4xr(a0b,32); f4xr(a1a,32); f4xr(a1b,32);
        f4xr(a2a,32); f4xr(a2b,32); f4xr(a3a,32); f4xr(a3b,32);
        if (lane < 16) {   // one group's worth of lanes per wave writes
            float* pr = ppw + wv*512 + qq*8;
            *(float4*)(pr +   0) = a0a; *(float4*)(pr +   4) = a0b;
            *(float4*)(pr + 128) = a1a; *(float4*)(pr + 132) = a1b;
            *(float4*)(pr + 256) = a2a; *(float4*)(pr + 260) = a2b;
            *(float4*)(pr + 384) = a3a; *(float4*)(pr + 388) = a3b;
        }
        __syncthreads();   // ppw + red ready

        if (tau < 4) {
            float ls = red[tau] + red[4+tau] + red[8+tau] + red[12+tau];
            if (slot >= 0) lpart[slot*4 + tau] = ls;
            else atomicAdd(&l_ovf[b*4 + tau], ls);
        }
        #pragma unroll
        for (int rep = 0; rep < 2; rep++) {
            int i = tau + rep*256;       // flat h*128+ch
            float v = ppw[i] + ppw[512 + i] + ppw[1024 + i] + ppw[1536 + i];
            if (slot >= 0) wpart[(long)slot*512 + i] = f2bf(v);
            else atomicAdd(&w_ovf[b*512 + i], v);
        }
        __syncthreads();   // ppw/red reuse next segment
    }
}

__global__ __launch_bounds__(256, 4) void kF(
    const void* __restrict__ features, const int* __restrict__ batch_idx,
    float* __restrict__ ws)
{
    if (*(const int*)(ws + WS_FLAG)) kF_impl<true >(features, batch_idx, ws, blockIdx.x);
    else                             kF_impl<false>(features, batch_idx, ws, blockIdx.x);
}

// ---------------------------------------------------------------------------
// kE: per batch (64 x 256) — unchanged from round 6/7.
template<bool BF16>
__device__ void kE_impl(int b, int tid, float* ws,
    const void* Wtok, const void* btok, const void* Wv, const void* bv,
    const void* Wiv, const void* biv, const void* Wo, const void* bo,
    const void* Wco, const void* bco, const void* Wout, const void* bout,
    void* out, float* sh, int* shi)
{
    using L = Ld<BF16>;
    float* wb   = sh;            // 512
    float* s1a  = sh + 512;      // 512
    float* s2a  = sh + 1024;     // 512
    float* ctxa = sh + 1536;     // 128
    float* aoa  = sh + 1664;     // 128
    float* y2a  = sh + 1792;     // 512
    float* p1k  = sh + 2304;     // 1024
    float* linv = sh + 3328;     // 4

    const int c = tid & 127, pair = tid >> 7;
    const int* cnti = (const int*)ws;
    const ushort_t* wpart = (const ushort_t*)(ws + WS_WPART);

    int n = cnti[WS_CNT + b]; if (n > 32) n = 32;
    if (tid < 32) shi[tid] = (tid < n) ? cnti[WS_SLOT + b*32 + tid] : 0;
    __syncthreads();

    float a0 = 0.f, a1 = 0.f, lac = 0.f;
    for (int i = 0; i < n; i++) {
        int s = shi[i];
        a0 += bf2f(wpart[(long)s*512 + tid]);
        a1 += bf2f(wpart[(long)s*512 + tid + 256]);
    }
    if (tid < 4) for (int i = 0; i < n; i++) lac += ws[WS_LPART + shi[i]*4 + tid];
    a0 += ws[WS_WOVF + b*512 + tid];
    a1 += ws[WS_WOVF + b*512 + tid + 256];
    if (tid < 4) {
        lac += ws[WS_LOVF + b*4 + tid];
        linv[tid] = (lac > 1e-30f) ? 1.f/lac : 0.f;
    }
    __syncthreads();
    wb[tid]     = a0 * linv[tid >> 7];
    wb[tid+256] = a1 * linv[(tid+256) >> 7];
    __syncthreads();

    {   // s1[h][c] = wbar_h @ Wtok[:,c]
        float b0=0.f,b1=0.f,b2=0.f,b3=0.f;
        #pragma unroll
        for (int k4 = 0; k4 < 64; k4 += 4) {
            int kk = pair*64 + k4;
            float wa = L::at(Wtok,(long)kk*128+c),     wbv = L::at(Wtok,(long)(kk+1)*128+c);
            float wc = L::at(Wtok,(long)(kk+2)*128+c), wd  = L::at(Wtok,(long)(kk+3)*128+c);
            float4 w0 = *(const float4*)&wb[kk],     w1 = *(const float4*)&wb[128+kk];
            float4 w2 = *(const float4*)&wb[256+kk], w3 = *(const float4*)&wb[384+kk];
            b0 += wa*w0.x + wbv*w0.y + wc*w0.z + wd*w0.w;
            b1 += wa*w1.x + wbv*w1.y + wc*w1.z + wd*w1.w;
            b2 += wa*w2.x + wbv*w2.y + wc*w2.z + wd*w2.w;
            b3 += wa*w3.x + wbv*w3.y + wc*w3.z + wd*w3.w;
        }
        p1k[pair*512 +   0 + c] = b0; p1k[pair*512 + 128 + c] = b1;
        p1k[pair*512 + 256 + c] = b2; p1k[pair*512 + 384 + c] = b3;
    }
    __syncthreads();
    s1a[tid]     = p1k[tid]     + p1k[512+tid]     + L::at(btok, tid & 127);
    s1a[tid+256] = p1k[tid+256] + p1k[768+tid]     + L::at(btok, (tid+256) & 127);
    __syncthreads();
    {   // s2[h][c] = s1_h @ Wv[:,c] + bv
        float b0=0.f,b1=0.f,b2=0.f,b3=0.f;
        #pragma unroll
        for (int k4 = 0; k4 < 64; k4 += 4) {
            int kk = pair*64 + k4;
            float wa = L::at(Wv,(long)kk*128+c),     wbv = L::at(Wv,(long)(kk+1)*128+c);
            float wc = L::at(Wv,(long)(kk+2)*128+c), wd  = L::at(Wv,(long)(kk+3)*128+c);
            float4 w0 = *(const float4*)&s1a[kk],     w1 = *(const float4*)&s1a[128+kk];
            float4 w2 = *(const float4*)&s1a[256+kk], w3 = *(const float4*)&s1a[384+kk];
            b0 += wa*w0.x + wbv*w0.y + wc*w0.z + wd*w0.w;
            b1 += wa*w1.x + wbv*w1.y + wc*w1.z + wd*w1.w;
            b2 += wa*w2.x + wbv*w2.y + wc*w2.z + wd*w2.w;
            b3 += wa*w3.x + wbv*w3.y + wc*w3.z + wd*w3.w;
        }
        p1k[pair*512 +   0 + c] = b0; p1k[pair*512 + 128 + c] = b1;
        p1k[pair*512 + 256 + c] = b2; p1k[pair*512 + 384 + c] = b3;
    }
    __syncthreads();
    s2a[tid]     = p1k[tid]     + p1k[512+tid] + L::at(bv, tid & 127);
    s2a[tid+256] = p1k[tid+256] + p1k[768+tid] + L::at(bv, (tid+256) & 127);
    __syncthreads();
    {   // ctx[o]= s2_h @ Wiv[:, o]
        int h = c >> 5;
        float acc = 0.f;
        #pragma unroll
        for (int k4 = 0; k4 < 64; k4 += 4) {
            int kk = pair*64 + k4;
            float4 s4 = *(const float4*)&s2a[h*128 + kk];
            acc += s4.x*L::at(Wiv,(long)kk*128+c)     + s4.y*L::at(Wiv,(long)(kk+1)*128+c)
                 + s4.z*L::at(Wiv,(long)(kk+2)*128+c) + s4.w*L::at(Wiv,(long)(kk+3)*128+c);
        }
        p1k[pair*128 + c] = acc;
    }
    __syncthreads();
    if (tid < 128) ctxa[tid] = p1k[tid] + p1k[128+tid] + L::at(biv, tid);
    __syncthreads();
    {   // ao = ctx @ Wo + bo
        float acc = 0.f;
        #pragma unroll
        for (int k4 = 0; k4 < 64; k4 += 4) {
            int kk = pair*64 + k4;
            float4 c4 = *(const float4*)&ctxa[kk];
            acc += c4.x*L::at(Wo,(long)kk*128+c)     + c4.y*L::at(Wo,(long)(kk+1)*128+c)
                 + c4.z*L::at(Wo,(long)(kk+2)*128+c) + c4.w*L::at(Wo,(long)(kk+3)*128+c);
        }
        p1k[pair*128 + c] = acc;
    }
    __syncthreads();
    if (tid < 128) aoa[tid] = p1k[tid] + p1k[128+tid] + L::at(bo, tid);
    __syncthreads();
    {   // y2 = ao @ Wco + bco
        float acc0 = 0.f, acc1 = 0.f;
        #pragma unroll
        for (int k = 0; k < 128; k += 4) {
            float4 a4 = *(const float4*)&aoa[k];
            acc0 += a4.x*L::at(Wco,(long)k*512+tid)     + a4.y*L::at(Wco,(long)(k+1)*512+tid)
                  + a4.z*L::at(Wco,(long)(k+2)*512+tid) + a4.w*L::at(Wco,(long)(k+3)*512+tid);
            acc1 += a4.x*L::at(Wco,(long)k*512+tid+256)     + a4.y*L::at(Wco,(long)(k+1)*512+tid+256)
                  + a4.z*L::at(Wco,(long)(k+2)*512+tid+256) + a4.w*L::at(Wco,(long)(k+3)*512+tid+256);
        }
        y2a[tid]     = acc0 + L::at(bco, tid);
        y2a[tid+256] = acc1 + L::at(bco, tid+256);
    }
    __syncthreads();
    for (int o = 0; o < 3; o++) {
        float p = y2a[tid]*L::at(Wout,(long)tid*3+o)
                + y2a[tid+256]*L::at(Wout,(long)(tid+256)*3+o);
        p1k[tid] = p; __syncthreads();
        for (int st = 128; st > 0; st >>= 1) {
            if (tid < st) p1k[tid] += p1k[tid+st];
            __syncthreads();
        }
        if (tid == 0) {
            float val = p1k[0] + L::at(bout, o);
            if (BF16) ((ushort_t*)out)[b*3+o] = f2bf(val);
            else      ((float*)out)[b*3+o] = val;
        }
        __syncthreads();
    }
}

__global__ __launch_bounds__(256) void kE(
    float* ws,
    const void* Wtok, const void* btok, const void* Wv, const void* bv,
    const void* Wiv, const void* biv, const void* Wo, const void* bo,
    const void* Wco, const void* bco, const void* Wout, const void* bout,
    void* out)
{
    __shared__ float sh[3332];
    __shared__ int shi[32];
    if (*(const int*)(ws + WS_FLAG))
        kE_impl<true >(blockIdx.x, threadIdx.x, ws, Wtok,btok,Wv,bv,Wiv,biv,
                       Wo,bo,Wco,bco,Wout,bout,out,sh,shi);
    else
        kE_impl<false>(blockIdx.x, threadIdx.x, ws, Wtok,btok,Wv,bv,Wiv,biv,
                       Wo,bo,Wco,bco,Wout,bout,out,sh,shi);
}

// ---------------------------------------------------------------------------
extern "C" void kernel_launch(void* const* d_in, const int* in_sizes, int n_in,
                              void* d_out, int out_size, void* d_ws, size_t ws_size,
                              hipStream_t stream)
{
    const void* features = d_in[0];
    const int*  batch_idx= (const int*)d_in[1];
    const void* y_t      = d_in[2];
    const int*  t        = (const int*)d_in[3];
    // d_in[4] = N_max (unused)
    const void *Wtok=d_in[5],  *btok=d_in[6];
    const void *Wt  =d_in[7],  *bt  =d_in[8];
    const void *Win =d_in[9],  *bin_=d_in[10];
    const void *Wq  =d_in[11], *bq  =d_in[12];
    const void *Wk  =d_in[13], *bk  =d_in[14];
    const void *Wv  =d_in[15], *bv  =d_in[16];
    const void *Wiq =d_in[17], *biq =d_in[18];
    const void *Wik =d_in[19], *bik =d_in[20];
    const void *Wiv =d_in[21], *biv =d_in[22];
    const void *Wo  =d_in[23], *bo  =d_in[24];
    const void *Wco =d_in[25], *bco =d_in[26];
    const void *Wout=d_in[27], *bout=d_in[28];

    int N = in_sizes[0] / CENC;   // 131072
    float* ws = (float*)d_ws;

    kA<<<NB, 256, 0, stream>>>((const ushort_t*)features, y_t, t,
        Wt, bt, Win, bin_, Wq, bq, Wiq, biq, Wtok, btok, Wk, bk, Wik, bik, ws);
    kF<<<N / 128, 256, 0, stream>>>(features, batch_idx, ws);
    kE<<<NB, 256, 0, stream>>>(ws, Wtok, btok, Wv, bv, Wiv, biv, Wo, bo,
                               Wco, bco, Wout, bout, d_out);
}